// Round 5
// baseline (403.631 us; speedup 1.0000x reference)
//
#include <hip/hip_runtime.h>
#include <math.h>

#define HEADS 4
#define NEG_SLOPE 0.2f

// ---------------- workspace layout (bytes) ----------------
// region A: h1 f32 (51.2M); later h2 f32 @0 (12.8M) + out2 f32 @12.8M (12.8M)
// region B: xhi/xlo bf16 (12.8M each); later out1hi/out1lo bf16 (25.6M each)
static constexpr size_t OFF_H1   = 0;
static constexpr size_t OFF_OUT2 = 12800000;
static constexpr size_t OFF_XHI  = 51200000;
static constexpr size_t OFF_XLO  = 64000000;
static constexpr size_t OFF_O1HI = 51200000;   // aliases xhi/xlo (dead by then)
static constexpr size_t OFF_O1LO = 76800000;
static constexpr size_t OFF_W1TH = 102400000;  // 256x128 bf16 = 64KB
static constexpr size_t OFF_W1TL = 102465536;
static constexpr size_t OFF_W2TH = 102531072;  // 64x256 bf16 = 32KB
static constexpr size_t OFF_W2TL = 102563840;
static constexpr size_t OFF_AS   = 102600000;  // 800,000
static constexpr size_t OFF_AD   = 103400000;  // 800,000
static constexpr size_t OFF_RP   = 104200000;  // 200,064
static constexpr size_t OFF_CUR  = 104400064;
static constexpr size_t OFF_CNT  = 104600128;
static constexpr size_t OFF_CSR  = 104800192;  // 1.6M
static constexpr size_t OFF_STRT = 106400192;
static constexpr size_t OFF_BSUM = 106400704;
static constexpr size_t OFF_BOFF = 106401216;

typedef __attribute__((ext_vector_type(8))) short short8;
typedef __attribute__((ext_vector_type(4))) float f32x4;

// ---------------- helpers ----------------
__device__ __forceinline__ float4 f4add(float4 a, float4 b) {
    return make_float4(a.x + b.x, a.y + b.y, a.z + b.z, a.w + b.w);
}
__device__ __forceinline__ float lrelu(float x) { return x > 0.f ? x : NEG_SLOPE * x; }
__device__ __forceinline__ float4 f4lrelu(float4 a) {
    return make_float4(lrelu(a.x), lrelu(a.y), lrelu(a.z), lrelu(a.w));
}
__device__ __forceinline__ float4 f4exp(float4 a) {
    return make_float4(__expf(a.x), __expf(a.y), __expf(a.z), __expf(a.w));
}
__device__ __forceinline__ float pickh(float4 v, int head) {
    float r = v.x;
    r = head == 1 ? v.y : r;
    r = head == 2 ? v.z : r;
    r = head == 3 ? v.w : r;
    return r;
}
// round-to-nearest bf16 (no NaN in this workload)
__device__ __forceinline__ unsigned short bfr(float x) {
    union { float f; unsigned u; } c; c.f = x;
    unsigned r = c.u + 0x7FFFu + ((c.u >> 16) & 1u);
    return (unsigned short)(r >> 16);
}
__device__ __forceinline__ float bf2f(unsigned short h) {
    union { unsigned u; float f; } c; c.u = ((unsigned)h) << 16;
    return c.f;
}

// ---------------- split kernels ----------------
// f32 -> (hi, lo) bf16 pair; lo = bf16(x - f32(hi)); grid-stride over float4s
__global__ void split_kernel(const float* __restrict__ in, unsigned short* __restrict__ hi,
                             unsigned short* __restrict__ lo, int n4)
{
    int i = blockIdx.x * 256 + threadIdx.x;
    const int stride = gridDim.x * 256;
    for (; i < n4; i += stride) {
        float4 v = ((const float4*)in)[i];
        unsigned short h0 = bfr(v.x), h1 = bfr(v.y), h2 = bfr(v.z), h3 = bfr(v.w);
        unsigned short l0 = bfr(v.x - bf2f(h0)), l1 = bfr(v.y - bf2f(h1));
        unsigned short l2 = bfr(v.z - bf2f(h2)), l3 = bfr(v.w - bf2f(h3));
        uint2 hp = make_uint2((unsigned)h0 | ((unsigned)h1 << 16),
                              (unsigned)h2 | ((unsigned)h3 << 16));
        uint2 lp = make_uint2((unsigned)l0 | ((unsigned)l1 << 16),
                              (unsigned)l2 | ((unsigned)l3 << 16));
        ((uint2*)hi)[i] = hp;
        ((uint2*)lo)[i] = lp;
    }
}

// W[K][N] f32 -> WT_hi/lo[N][K] bf16 (transpose + split; tiny matrices)
__global__ void wsplit_kernel(const float* __restrict__ W, unsigned short* __restrict__ hiT,
                              unsigned short* __restrict__ loT, int K, int N)
{
    int n = blockIdx.x * 64 + threadIdx.x;
    if (n >= N) return;
    for (int k = 0; k < K; ++k) {
        float v = W[(size_t)k * N + n];
        unsigned short h = bfr(v);
        hiT[(size_t)n * K + k] = h;
        loT[(size_t)n * K + k] = bfr(v - bf2f(h));
    }
}

// ---------------- MFMA GEMM with GAT-alpha epilogue ----------------
// C[M,N] = A[M,K]·B[K,N] via split-bf16 3-pass (AhiBhi + AhiBlo + AloBhi).
// A given as (Ahi,Alo)[M][K] bf16 rows; B as (BThi,BTlo)[N][K] bf16 rows (B^T).
// 256 threads = 4 waves in WRxWC grid; frag = mfma_f32_16x16x32_bf16 (verified
// C layout: col=lane&15, row=(lane>>4)*4+reg).
// alpha_{s,d}[m,h] = sum_c C[m,h*CPH+c]*avec[h,c] via per-frag 16-lane reduce.
template<int BM, int BN, int KDIM, int WR, int WC, int CPH>
__global__ __launch_bounds__(256, 2)
void mfma_gemm_gat(const unsigned short* __restrict__ Ahi, const unsigned short* __restrict__ Alo,
                   const unsigned short* __restrict__ BThi, const unsigned short* __restrict__ BTlo,
                   float* __restrict__ C,
                   const float* __restrict__ avec_s, const float* __restrict__ avec_d,
                   float* __restrict__ alpha_s, float* __restrict__ alpha_d,
                   int M, int N)
{
    constexpr int BK    = 32;
    constexpr int WROWS = BM / WR;
    constexpr int WCOLS = BN / WC;
    constexpr int FR    = WROWS / 16;
    constexpr int FC    = WCOLS / 16;
    constexpr int AP    = (BM * (BK / 8)) / 256;   // 16B staging pieces per thread
    constexpr int BP    = (BN * (BK / 8)) / 256;
    static_assert(AP >= 1 && BP >= 1, "tile too small");

    __shared__ short As_hi[BM * BK], As_lo[BM * BK];
    __shared__ short Bs_hi[BN * BK], Bs_lo[BN * BK];

    const int tid  = threadIdx.x;
    const int w    = tid >> 6, lane = tid & 63;
    const int wr   = w / WC, wc = w % WC;
    const int lrow = lane & 15, lk = lane >> 4;
    const int m0   = blockIdx.x * BM, n0 = blockIdx.y * BN;

    f32x4 acc[FR][FC];
#pragma unroll
    for (int i = 0; i < FR; ++i)
#pragma unroll
        for (int j = 0; j < FC; ++j) acc[i][j] = (f32x4){0.f, 0.f, 0.f, 0.f};

    short8 rAh[AP], rAl[AP], rBh[BP], rBl[BP];

    auto LOAD = [&](int kb) {
#pragma unroll
        for (int p = 0; p < AP; ++p) {
            int id = p * 256 + tid;
            int r = id >> 2, c = id & 3;
            int row = m0 + r; row = row < M ? row : M - 1;
            size_t off = (size_t)row * KDIM + kb + c * 8;
            rAh[p] = *(const short8*)(Ahi + off);
            rAl[p] = *(const short8*)(Alo + off);
        }
#pragma unroll
        for (int p = 0; p < BP; ++p) {
            int id = p * 256 + tid;
            int r = id >> 2, c = id & 3;
            size_t off = (size_t)(n0 + r) * KDIM + kb + c * 8;
            rBh[p] = *(const short8*)(BThi + off);
            rBl[p] = *(const short8*)(BTlo + off);
        }
    };
    auto STORE = [&]() {
#pragma unroll
        for (int p = 0; p < AP; ++p) {
            int id = p * 256 + tid;
            int r = id >> 2, c = id & 3;
            *(short8*)(&As_hi[r * BK + c * 8]) = rAh[p];
            *(short8*)(&As_lo[r * BK + c * 8]) = rAl[p];
        }
#pragma unroll
        for (int p = 0; p < BP; ++p) {
            int id = p * 256 + tid;
            int r = id >> 2, c = id & 3;
            *(short8*)(&Bs_hi[r * BK + c * 8]) = rBh[p];
            *(short8*)(&Bs_lo[r * BK + c * 8]) = rBl[p];
        }
    };

    constexpr int NT = KDIM / BK;
    LOAD(0);
    for (int t = 0; t < NT; ++t) {
        STORE();
        __syncthreads();
        if (t + 1 < NT) LOAD((t + 1) * BK);

        short8 afh[FR], afl[FR], bfh[FC], bfl[FC];
#pragma unroll
        for (int fr = 0; fr < FR; ++fr) {
            int r = wr * WROWS + fr * 16 + lrow;
            afh[fr] = *(const short8*)(&As_hi[r * BK + lk * 8]);
            afl[fr] = *(const short8*)(&As_lo[r * BK + lk * 8]);
        }
#pragma unroll
        for (int fc = 0; fc < FC; ++fc) {
            int r = wc * WCOLS + fc * 16 + lrow;
            bfh[fc] = *(const short8*)(&Bs_hi[r * BK + lk * 8]);
            bfl[fc] = *(const short8*)(&Bs_lo[r * BK + lk * 8]);
        }
#pragma unroll
        for (int fr = 0; fr < FR; ++fr)
#pragma unroll
            for (int fc = 0; fc < FC; ++fc) {
                acc[fr][fc] = __builtin_amdgcn_mfma_f32_16x16x32_bf16(afh[fr], bfh[fc], acc[fr][fc], 0, 0, 0);
                acc[fr][fc] = __builtin_amdgcn_mfma_f32_16x16x32_bf16(afh[fr], bfl[fc], acc[fr][fc], 0, 0, 0);
                acc[fr][fc] = __builtin_amdgcn_mfma_f32_16x16x32_bf16(afl[fr], bfh[fc], acc[fr][fc], 0, 0, 0);
            }
        __syncthreads();
    }

    // epilogue: C store + alpha partial dots (no atomics; one wave owns each (row,head))
#pragma unroll
    for (int fr = 0; fr < FR; ++fr) {
        const int rbase = m0 + wr * WROWS + fr * 16 + lk * 4;
        float ps[4] = {0.f, 0.f, 0.f, 0.f}, pd[4] = {0.f, 0.f, 0.f, 0.f};
#pragma unroll
        for (int fc = 0; fc < FC; ++fc) {
            const int gc   = n0 + wc * WCOLS + fc * 16 + lrow;
            const int head = gc / CPH, ci = gc % CPH;
            const float asv = avec_s[head * CPH + ci];
            const float adv = avec_d[head * CPH + ci];
#pragma unroll
            for (int rg = 0; rg < 4; ++rg) {
                int row = rbase + rg;
                float v = acc[fr][fc][rg];
                if (row < M) C[(size_t)row * N + gc] = v;
                ps[rg] += v * asv;
                pd[rg] += v * adv;
            }
            if constexpr (CPH == 16) {
#pragma unroll
                for (int rg = 0; rg < 4; ++rg) {
                    float s = ps[rg], d = pd[rg];
#pragma unroll
                    for (int m = 1; m <= 8; m <<= 1) {
                        s += __shfl_xor(s, m);
                        d += __shfl_xor(d, m);
                    }
                    if (lrow == 0 && rbase + rg < M) {
                        alpha_s[(size_t)(rbase + rg) * HEADS + head] = s;
                        alpha_d[(size_t)(rbase + rg) * HEADS + head] = d;
                    }
                    ps[rg] = 0.f; pd[rg] = 0.f;
                }
            }
        }
        if constexpr (CPH != 16) {
            const int head = (n0 + wc * WCOLS) / CPH;
#pragma unroll
            for (int rg = 0; rg < 4; ++rg) {
                float s = ps[rg], d = pd[rg];
#pragma unroll
                for (int m = 1; m <= 8; m <<= 1) {
                    s += __shfl_xor(s, m);
                    d += __shfl_xor(d, m);
                }
                if (lrow == 0 && rbase + rg < M) {
                    alpha_s[(size_t)(rbase + rg) * HEADS + head] = s;
                    alpha_d[(size_t)(rbase + rg) * HEADS + head] = d;
                }
            }
        }
    }
}

// ---------------- CSR build ----------------
__global__ void count_kernel(const int* __restrict__ dst, int* __restrict__ counts, int E)
{
    int e = blockIdx.x * 256 + threadIdx.x;
    if (e < E) atomicAdd(&counts[dst[e]], 1);
}

__global__ void scatter_kernel(const int* __restrict__ src, const int* __restrict__ dst,
                               int* __restrict__ cursor, int* __restrict__ csr, int E)
{
    int e = blockIdx.x * 256 + threadIdx.x;
    if (e < E) {
        int d   = dst[e];
        int pos = atomicAdd(&cursor[d], 1);
        csr[pos] = src[e];
    }
}

// ---------------- parallel scan (3 kernels) ----------------
__global__ __launch_bounds__(1024)
void scan_block_kernel(const int* __restrict__ counts, int* __restrict__ excl_out,
                       int* __restrict__ bsum, int n)
{
    __shared__ int wsum[16];
    const int t = threadIdx.x, lane = t & 63, w = t >> 6;
    const int i = blockIdx.x * 1024 + t;
    int v = (i < n) ? counts[i] : 0;
    int x = v;
#pragma unroll
    for (int d = 1; d < 64; d <<= 1) {
        int y = __shfl_up(x, d);
        if (lane >= d) x += y;
    }
    if (lane == 63) wsum[w] = x;
    __syncthreads();
    if (t < 16) {
        int s = wsum[t];
#pragma unroll
        for (int d = 1; d < 16; d <<= 1) {
            int y = __shfl_up(s, d);
            if (t >= d) s += y;
        }
        wsum[t] = s;
    }
    __syncthreads();
    int wbase = (w > 0) ? wsum[w - 1] : 0;
    if (i < n) excl_out[i] = wbase + x - v;
    if (t == 1023) bsum[blockIdx.x] = wsum[15];
}

__global__ void scan_tops_kernel(const int* __restrict__ bsum, int* __restrict__ boff,
                                 int* __restrict__ row_ptr, int nb, int n)
{
    const int t = threadIdx.x;   // 64 threads, one wave
    int v = (t < nb) ? bsum[t] : 0;
    int x = v;
#pragma unroll
    for (int d = 1; d < 64; d <<= 1) {
        int y = __shfl_up(x, d);
        if (t >= d) x += y;
    }
    if (t < nb) boff[t] = x - v;
    if (t == 63) row_ptr[n] = x;
}

__global__ __launch_bounds__(1024)
void scan_add_kernel(const int* __restrict__ boff, int* __restrict__ row_ptr,
                     int* __restrict__ cursor, int n)
{
    const int i = blockIdx.x * 1024 + threadIdx.x;
    if (i < n) {
        int r = row_ptr[i] + boff[blockIdx.x];
        row_ptr[i] = r;
        cursor[i]  = r;
    }
}

// ---------------- GAT softmax + aggregation ----------------
// One wave per destination node. No max-shift (|e| is O(1), far from f32 exp
// limits). CH=256 writes split-bf16 (hi,lo) for the next MFMA GEMM;
// CH=64 writes f32.
template<int CH>
__global__ __launch_bounds__(256)
void gat_agg(const float* __restrict__ h, const float* __restrict__ alpha_s,
             const float* __restrict__ alpha_d, const int* __restrict__ row_ptr,
             const int* __restrict__ csr_src, const float* __restrict__ bias,
             float* __restrict__ out, unsigned short* __restrict__ out_hi,
             unsigned short* __restrict__ out_lo, int n)
{
    __shared__ float wls[4][64 * 5];   // [wave][j*5+h] stride-5: conflict-free
    __shared__ int   sls[4][64];
    const int wid  = threadIdx.x >> 6;
    const int lane = threadIdx.x & 63;
    const int node = blockIdx.x * 4 + wid;
    if (node >= n) return;
    const int head = lane >> 4;
    const int p0 = row_ptr[node], p1 = row_ptr[node + 1];
    const int deg = p1 - p0;

    const float4 asn = *(const float4*)(alpha_s + (size_t)node * 4);
    const float4 adn = *(const float4*)(alpha_d + (size_t)node * 4);
    float4 den = f4exp(f4lrelu(f4add(asn, adn)));   // self-loop term
    const float wse = pickh(den, head);

    float4 acc4 = make_float4(0.f, 0.f, 0.f, 0.f);
    float  acc1 = 0.f;
    if constexpr (CH == 256) {
        float4 hv = *(const float4*)(h + (size_t)node * CH + lane * 4);
        acc4 = make_float4(wse * hv.x, wse * hv.y, wse * hv.z, wse * hv.w);
    } else {
        acc1 = wse * h[(size_t)node * CH + lane];
    }

    for (int ch = 0; ch < deg; ch += 64) {
        const int cnt = min(64, deg - ch);
        float4 w4 = make_float4(0.f, 0.f, 0.f, 0.f);
        int sl = 0;
        if (lane < cnt) {
            sl = csr_src[p0 + ch + lane];
            float4 al = *(const float4*)(alpha_s + (size_t)sl * 4);
            w4 = f4exp(f4lrelu(f4add(al, adn)));
        }
        float4 t = w4;
#pragma unroll
        for (int d = 32; d >= 1; d >>= 1) {
            t.x += __shfl_xor(t.x, d);
            t.y += __shfl_xor(t.y, d);
            t.z += __shfl_xor(t.z, d);
            t.w += __shfl_xor(t.w, d);
        }
        den = f4add(den, t);
        sls[wid][lane] = sl;
        wls[wid][lane * 5 + 0] = w4.x;
        wls[wid][lane * 5 + 1] = w4.y;
        wls[wid][lane * 5 + 2] = w4.z;
        wls[wid][lane * 5 + 3] = w4.w;

        for (int j = 0; j < cnt; ++j) {
            int   sj = sls[wid][j];
            float w  = wls[wid][j * 5 + head];
            if constexpr (CH == 256) {
                float4 hv = *(const float4*)(h + (size_t)sj * CH + lane * 4);
                acc4.x += w * hv.x; acc4.y += w * hv.y;
                acc4.z += w * hv.z; acc4.w += w * hv.w;
            } else {
                acc1 += w * h[(size_t)sj * CH + lane];
            }
        }
    }

    const float invd = 1.0f / (pickh(den, head) + 1e-16f);
    if constexpr (CH == 256) {
        int c0 = lane * 4;
        float o0 = fmaxf(acc4.x * invd + bias[c0 + 0], 0.f);
        float o1 = fmaxf(acc4.y * invd + bias[c0 + 1], 0.f);
        float o2 = fmaxf(acc4.z * invd + bias[c0 + 2], 0.f);
        float o3 = fmaxf(acc4.w * invd + bias[c0 + 3], 0.f);
        unsigned short h0 = bfr(o0), h1 = bfr(o1), h2 = bfr(o2), h3 = bfr(o3);
        unsigned short l0 = bfr(o0 - bf2f(h0)), l1 = bfr(o1 - bf2f(h1));
        unsigned short l2 = bfr(o2 - bf2f(h2)), l3 = bfr(o3 - bf2f(h3));
        *(uint2*)(out_hi + (size_t)node * CH + c0) =
            make_uint2((unsigned)h0 | ((unsigned)h1 << 16), (unsigned)h2 | ((unsigned)h3 << 16));
        *(uint2*)(out_lo + (size_t)node * CH + c0) =
            make_uint2((unsigned)l0 | ((unsigned)l1 << 16), (unsigned)l2 | ((unsigned)l3 << 16));
    } else {
        out[(size_t)node * CH + lane] = fmaxf(acc1 * invd + bias[lane], 0.f);
    }
}

// ---------------- graph boundaries + fused mean-pool/FC ----------------
__global__ void graph_starts_kernel(const int* __restrict__ batch, int* __restrict__ starts,
                                    int n, int ngraphs)
{
    int g = threadIdx.x;
    if (g > ngraphs) return;
    int lo = 0, hi = n;
    while (lo < hi) {
        int mid = (lo + hi) >> 1;
        if (batch[mid] < g) lo = mid + 1; else hi = mid;
    }
    starts[g] = lo;
}

__global__ __launch_bounds__(256)
void pool_fc_kernel(const float* __restrict__ feat, const int* __restrict__ starts,
                    const float* __restrict__ Wfc, const float* __restrict__ bfc,
                    float* __restrict__ out)
{
    __shared__ float4 part[16][16];
    __shared__ float pooled[64];
    const int g = blockIdx.x;
    const int t = threadIdx.x;
    const int q = t & 15, ns = t >> 4;
    const int s0 = starts[g], s1 = starts[g + 1];
    float4 acc = make_float4(0.f, 0.f, 0.f, 0.f);
    for (int i = s0 + ns; i < s1; i += 16)
        acc = f4add(acc, *(const float4*)(feat + (size_t)i * 64 + q * 4));
    part[ns][q] = acc;
    __syncthreads();
    if (t < 16) {
        float4 s = part[0][t];
#pragma unroll
        for (int k = 1; k < 16; ++k) s = f4add(s, part[k][t]);
        float inv = 1.0f / fmaxf((float)(s1 - s0), 1.0f);
        pooled[t * 4 + 0] = s.x * inv;
        pooled[t * 4 + 1] = s.y * inv;
        pooled[t * 4 + 2] = s.z * inv;
        pooled[t * 4 + 3] = s.w * inv;
    }
    __syncthreads();
    if (t < 2) {
        float a = bfc[t];
        for (int c = 0; c < 64; ++c) a += pooled[c] * Wfc[c * 2 + t];
        out[g * 2 + t] = a;
    }
}

// ---------------- launch ----------------
extern "C" void kernel_launch(void* const* d_in, const int* in_sizes, int n_in,
                              void* d_out, int out_size, void* d_ws, size_t ws_size,
                              hipStream_t stream)
{
    const float* x    = (const float*)d_in[0];
    const int*   ei   = (const int*)d_in[1];
    const int*   batch= (const int*)d_in[2];
    const float* W1   = (const float*)d_in[3];
    const float* as1  = (const float*)d_in[4];
    const float* ad1  = (const float*)d_in[5];
    const float* b1   = (const float*)d_in[6];
    const float* W2   = (const float*)d_in[7];
    const float* as2  = (const float*)d_in[8];
    const float* ad2  = (const float*)d_in[9];
    const float* b2   = (const float*)d_in[10];
    const float* Wfc  = (const float*)d_in[11];
    const float* bfc  = (const float*)d_in[12];
    float* out = (float*)d_out;

    const int N = in_sizes[2];          // 50000 nodes
    const int E = in_sizes[1] / 27;     // 400000 edges
    const int F = in_sizes[0] / N;      // 128

    char* ws = (char*)d_ws;
    float*          h1    = (float*)(ws + OFF_H1);
    float*          h2    = (float*)(ws + OFF_H1);
    float*          out2  = (float*)(ws + OFF_OUT2);
    unsigned short* xhi   = (unsigned short*)(ws + OFF_XHI);
    unsigned short* xlo   = (unsigned short*)(ws + OFF_XLO);
    unsigned short* o1hi  = (unsigned short*)(ws + OFF_O1HI);
    unsigned short* o1lo  = (unsigned short*)(ws + OFF_O1LO);
    unsigned short* w1th  = (unsigned short*)(ws + OFF_W1TH);
    unsigned short* w1tl  = (unsigned short*)(ws + OFF_W1TL);
    unsigned short* w2th  = (unsigned short*)(ws + OFF_W2TH);
    unsigned short* w2tl  = (unsigned short*)(ws + OFF_W2TL);
    float* al_s  = (float*)(ws + OFF_AS);
    float* al_d  = (float*)(ws + OFF_AD);
    int*   rp    = (int*)(ws + OFF_RP);
    int*   cur   = (int*)(ws + OFF_CUR);
    int*   cnt   = (int*)(ws + OFF_CNT);
    int*   csr   = (int*)(ws + OFF_CSR);
    int*   strt  = (int*)(ws + OFF_STRT);
    int*   bsum  = (int*)(ws + OFF_BSUM);
    int*   boff  = (int*)(ws + OFF_BOFF);

    const int egrid = (E + 255) / 256;
    const int NB    = (N + 1023) / 1024;   // scan blocks (49)

    // ---- splits ----
    split_kernel<<<2048, 256, 0, stream>>>(x, xhi, xlo, N * F / 4);
    wsplit_kernel<<<4, 64, 0, stream>>>(W1, w1th, w1tl, F, HEADS * 64);
    wsplit_kernel<<<1, 64, 0, stream>>>(W2, w2th, w2tl, HEADS * 64, HEADS * 16);

    // ---- layer 1: MFMA GEMM (M=50000, K=128, Ncols=256) ----
    {
        dim3 g((N + 127) / 128, 2);
        mfma_gemm_gat<128, 128, 128, 2, 2, 64><<<g, 256, 0, stream>>>(
            xhi, xlo, w1th, w1tl, h1, as1, ad1, al_s, al_d, N, HEADS * 64);
    }
    hipMemsetAsync(cnt, 0, (size_t)N * sizeof(int), stream);
    count_kernel<<<egrid, 256, 0, stream>>>(ei + 26 * (size_t)E, cnt, E);
    scan_block_kernel<<<NB, 1024, 0, stream>>>(cnt, rp, bsum, N);
    scan_tops_kernel<<<1, 64, 0, stream>>>(bsum, boff, rp, NB, N);
    scan_add_kernel<<<NB, 1024, 0, stream>>>(boff, rp, cur, N);
    scatter_kernel<<<egrid, 256, 0, stream>>>(ei + 17 * (size_t)E, ei + 26 * (size_t)E, cur, csr, E);
    gat_agg<256><<<(N + 3) / 4, 256, 0, stream>>>(h1, al_s, al_d, rp, csr, b1,
                                                  nullptr, o1hi, o1lo, N);

    // ---- layer 2: MFMA GEMM (M=50000, K=256, Ncols=64) ----
    {
        dim3 g((N + 63) / 64, 1);
        mfma_gemm_gat<64, 64, 256, 2, 2, 16><<<g, 256, 0, stream>>>(
            o1hi, o1lo, w2th, w2tl, h2, as2, ad2, al_s, al_d, N, HEADS * 16);
    }
    hipMemsetAsync(cnt, 0, (size_t)N * sizeof(int), stream);
    count_kernel<<<egrid, 256, 0, stream>>>(ei + 16 * (size_t)E, cnt, E);
    scan_block_kernel<<<NB, 1024, 0, stream>>>(cnt, rp, bsum, N);
    scan_tops_kernel<<<1, 64, 0, stream>>>(bsum, boff, rp, NB, N);
    scan_add_kernel<<<NB, 1024, 0, stream>>>(boff, rp, cur, N);
    scatter_kernel<<<egrid, 256, 0, stream>>>(ei + 15 * (size_t)E, ei + 16 * (size_t)E, cur, csr, E);
    gat_agg<64><<<(N + 3) / 4, 256, 0, stream>>>(h2, al_s, al_d, rp, csr, b2,
                                                 out2, nullptr, nullptr, N);

    // ---- pool + fc ----
    graph_starts_kernel<<<1, 65, 0, stream>>>(batch, strt, N, 64);
    pool_fc_kernel<<<64, 256, 0, stream>>>(out2, strt, Wfc, bfc, out);
}

// Round 6
// 288.229 us; speedup vs baseline: 1.4004x; 1.4004x over previous
//
#include <hip/hip_runtime.h>
#include <math.h>

#define HEADS 4
#define NEG_SLOPE 0.2f

// ---------------- workspace layout (bytes) ----------------
// region A: h1 f32 (51.2M); later h2 f32 @0 (12.8M) + out2 f32 @12.8M (12.8M)
// region B: xhi/xlo bf16 (12.8M each); later out1hi/out1lo bf16 (25.6M each)
static constexpr size_t OFF_H1   = 0;
static constexpr size_t OFF_OUT2 = 12800000;
static constexpr size_t OFF_XHI  = 51200000;
static constexpr size_t OFF_XLO  = 64000000;
static constexpr size_t OFF_O1HI = 51200000;   // aliases xhi/xlo (dead by then)
static constexpr size_t OFF_O1LO = 76800000;
static constexpr size_t OFF_W1TH = 102400000;  // 256x128 bf16 = 64KB
static constexpr size_t OFF_W1TL = 102465536;
static constexpr size_t OFF_W2TH = 102531072;  // 64x256 bf16 = 32KB
static constexpr size_t OFF_W2TL = 102563840;
static constexpr size_t OFF_AS   = 102600000;  // 800,000
static constexpr size_t OFF_AD   = 103400000;  // 800,000
static constexpr size_t OFF_RP   = 104200000;  // 200,064
static constexpr size_t OFF_CUR  = 104400064;
static constexpr size_t OFF_CNT  = 104600128;
static constexpr size_t OFF_CSR  = 104800192;  // 1.6M
static constexpr size_t OFF_STRT = 106400192;
static constexpr size_t OFF_BSUM = 106400704;
static constexpr size_t OFF_BOFF = 106401216;

typedef __attribute__((ext_vector_type(8))) short short8;
typedef __attribute__((ext_vector_type(4))) float f32x4;

// ---------------- helpers ----------------
__device__ __forceinline__ float4 f4add(float4 a, float4 b) {
    return make_float4(a.x + b.x, a.y + b.y, a.z + b.z, a.w + b.w);
}
__device__ __forceinline__ float lrelu(float x) { return x > 0.f ? x : NEG_SLOPE * x; }
__device__ __forceinline__ float4 f4lrelu(float4 a) {
    return make_float4(lrelu(a.x), lrelu(a.y), lrelu(a.z), lrelu(a.w));
}
__device__ __forceinline__ float4 f4exp(float4 a) {
    return make_float4(__expf(a.x), __expf(a.y), __expf(a.z), __expf(a.w));
}
__device__ __forceinline__ float pickh(float4 v, int head) {
    float r = v.x;
    r = head == 1 ? v.y : r;
    r = head == 2 ? v.z : r;
    r = head == 3 ? v.w : r;
    return r;
}
// round-to-nearest bf16 (no NaN in this workload)
__device__ __forceinline__ unsigned short bfr(float x) {
    union { float f; unsigned u; } c; c.f = x;
    unsigned r = c.u + 0x7FFFu + ((c.u >> 16) & 1u);
    return (unsigned short)(r >> 16);
}
__device__ __forceinline__ float bf2f(unsigned short h) {
    union { unsigned u; float f; } c; c.u = ((unsigned)h) << 16;
    return c.f;
}

// ---------------- split kernels ----------------
// f32 -> (hi, lo) bf16 pair; lo = bf16(x - f32(hi)); grid-stride over float4s
__global__ void split_kernel(const float* __restrict__ in, unsigned short* __restrict__ hi,
                             unsigned short* __restrict__ lo, int n4)
{
    int i = blockIdx.x * 256 + threadIdx.x;
    const int stride = gridDim.x * 256;
    for (; i < n4; i += stride) {
        float4 v = ((const float4*)in)[i];
        unsigned short h0 = bfr(v.x), h1 = bfr(v.y), h2 = bfr(v.z), h3 = bfr(v.w);
        unsigned short l0 = bfr(v.x - bf2f(h0)), l1 = bfr(v.y - bf2f(h1));
        unsigned short l2 = bfr(v.z - bf2f(h2)), l3 = bfr(v.w - bf2f(h3));
        uint2 hp = make_uint2((unsigned)h0 | ((unsigned)h1 << 16),
                              (unsigned)h2 | ((unsigned)h3 << 16));
        uint2 lp = make_uint2((unsigned)l0 | ((unsigned)l1 << 16),
                              (unsigned)l2 | ((unsigned)l3 << 16));
        ((uint2*)hi)[i] = hp;
        ((uint2*)lo)[i] = lp;
    }
}

// W[K][N] f32 -> WT_hi/lo[N][K] bf16 (transpose + split).
// One thread per element: coalesced read, tiny strided transpose write.
__global__ void wsplit_kernel(const float* __restrict__ W, unsigned short* __restrict__ hiT,
                              unsigned short* __restrict__ loT, int K, int N)
{
    int idx = blockIdx.x * 256 + threadIdx.x;
    if (idx >= K * N) return;
    int k = idx / N, n = idx - k * N;
    float v = W[idx];
    unsigned short h = bfr(v);
    hiT[(size_t)n * K + k] = h;
    loT[(size_t)n * K + k] = bfr(v - bf2f(h));
}

// ---------------- MFMA GEMM with GAT-alpha epilogue ----------------
// C[M,N] = A[M,K]·B[K,N] via split-bf16 3-pass (AhiBhi + AhiBlo + AloBhi).
// A given as (Ahi,Alo)[M][K] bf16 rows; B as (BThi,BTlo)[N][K] bf16 rows (B^T).
// 256 threads = 4 waves in WRxWC grid; frag = mfma_f32_16x16x32_bf16 (verified
// C layout: col=lane&15, row=(lane>>4)*4+reg).
// alpha_{s,d}[m,h] = sum_c C[m,h*CPH+c]*avec[h,c] via per-frag 16-lane reduce.
template<int BM, int BN, int KDIM, int WR, int WC, int CPH>
__global__ __launch_bounds__(256, 2)
void mfma_gemm_gat(const unsigned short* __restrict__ Ahi, const unsigned short* __restrict__ Alo,
                   const unsigned short* __restrict__ BThi, const unsigned short* __restrict__ BTlo,
                   float* __restrict__ C,
                   const float* __restrict__ avec_s, const float* __restrict__ avec_d,
                   float* __restrict__ alpha_s, float* __restrict__ alpha_d,
                   int M, int N)
{
    constexpr int BK    = 32;
    constexpr int WROWS = BM / WR;
    constexpr int WCOLS = BN / WC;
    constexpr int FR    = WROWS / 16;
    constexpr int FC    = WCOLS / 16;
    constexpr int AP    = (BM * (BK / 8)) / 256;   // 16B staging pieces per thread
    constexpr int BP    = (BN * (BK / 8)) / 256;
    static_assert(AP >= 1 && BP >= 1, "tile too small");

    __shared__ short As_hi[BM * BK], As_lo[BM * BK];
    __shared__ short Bs_hi[BN * BK], Bs_lo[BN * BK];

    const int tid  = threadIdx.x;
    const int w    = tid >> 6, lane = tid & 63;
    const int wr   = w / WC, wc = w % WC;
    const int lrow = lane & 15, lk = lane >> 4;
    const int m0   = blockIdx.x * BM, n0 = blockIdx.y * BN;

    f32x4 acc[FR][FC];
#pragma unroll
    for (int i = 0; i < FR; ++i)
#pragma unroll
        for (int j = 0; j < FC; ++j) acc[i][j] = (f32x4){0.f, 0.f, 0.f, 0.f};

    short8 rAh[AP], rAl[AP], rBh[BP], rBl[BP];

    auto LOAD = [&](int kb) {
#pragma unroll
        for (int p = 0; p < AP; ++p) {
            int id = p * 256 + tid;
            int r = id >> 2, c = id & 3;
            int row = m0 + r; row = row < M ? row : M - 1;
            size_t off = (size_t)row * KDIM + kb + c * 8;
            rAh[p] = *(const short8*)(Ahi + off);
            rAl[p] = *(const short8*)(Alo + off);
        }
#pragma unroll
        for (int p = 0; p < BP; ++p) {
            int id = p * 256 + tid;
            int r = id >> 2, c = id & 3;
            size_t off = (size_t)(n0 + r) * KDIM + kb + c * 8;
            rBh[p] = *(const short8*)(BThi + off);
            rBl[p] = *(const short8*)(BTlo + off);
        }
    };
    auto STORE = [&]() {
#pragma unroll
        for (int p = 0; p < AP; ++p) {
            int id = p * 256 + tid;
            int r = id >> 2, c = id & 3;
            *(short8*)(&As_hi[r * BK + c * 8]) = rAh[p];
            *(short8*)(&As_lo[r * BK + c * 8]) = rAl[p];
        }
#pragma unroll
        for (int p = 0; p < BP; ++p) {
            int id = p * 256 + tid;
            int r = id >> 2, c = id & 3;
            *(short8*)(&Bs_hi[r * BK + c * 8]) = rBh[p];
            *(short8*)(&Bs_lo[r * BK + c * 8]) = rBl[p];
        }
    };

    constexpr int NT = KDIM / BK;
    LOAD(0);
    for (int t = 0; t < NT; ++t) {
        STORE();
        __syncthreads();
        if (t + 1 < NT) LOAD((t + 1) * BK);

        short8 afh[FR], afl[FR], bfh[FC], bfl[FC];
#pragma unroll
        for (int fr = 0; fr < FR; ++fr) {
            int r = wr * WROWS + fr * 16 + lrow;
            afh[fr] = *(const short8*)(&As_hi[r * BK + lk * 8]);
            afl[fr] = *(const short8*)(&As_lo[r * BK + lk * 8]);
        }
#pragma unroll
        for (int fc = 0; fc < FC; ++fc) {
            int r = wc * WCOLS + fc * 16 + lrow;
            bfh[fc] = *(const short8*)(&Bs_hi[r * BK + lk * 8]);
            bfl[fc] = *(const short8*)(&Bs_lo[r * BK + lk * 8]);
        }
#pragma unroll
        for (int fr = 0; fr < FR; ++fr)
#pragma unroll
            for (int fc = 0; fc < FC; ++fc) {
                acc[fr][fc] = __builtin_amdgcn_mfma_f32_16x16x32_bf16(afh[fr], bfh[fc], acc[fr][fc], 0, 0, 0);
                acc[fr][fc] = __builtin_amdgcn_mfma_f32_16x16x32_bf16(afh[fr], bfl[fc], acc[fr][fc], 0, 0, 0);
                acc[fr][fc] = __builtin_amdgcn_mfma_f32_16x16x32_bf16(afl[fr], bfh[fc], acc[fr][fc], 0, 0, 0);
            }
        __syncthreads();
    }

    // epilogue: C store + alpha partial dots (no atomics; one wave owns each (row,head))
#pragma unroll
    for (int fr = 0; fr < FR; ++fr) {
        const int rbase = m0 + wr * WROWS + fr * 16 + lk * 4;
        float ps[4] = {0.f, 0.f, 0.f, 0.f}, pd[4] = {0.f, 0.f, 0.f, 0.f};
#pragma unroll
        for (int fc = 0; fc < FC; ++fc) {
            const int gc   = n0 + wc * WCOLS + fc * 16 + lrow;
            const int head = gc / CPH, ci = gc % CPH;
            const float asv = avec_s[head * CPH + ci];
            const float adv = avec_d[head * CPH + ci];
#pragma unroll
            for (int rg = 0; rg < 4; ++rg) {
                int row = rbase + rg;
                float v = acc[fr][fc][rg];
                if (row < M) C[(size_t)row * N + gc] = v;
                ps[rg] += v * asv;
                pd[rg] += v * adv;
            }
            if constexpr (CPH == 16) {
#pragma unroll
                for (int rg = 0; rg < 4; ++rg) {
                    float s = ps[rg], d = pd[rg];
#pragma unroll
                    for (int m = 1; m <= 8; m <<= 1) {
                        s += __shfl_xor(s, m);
                        d += __shfl_xor(d, m);
                    }
                    if (lrow == 0 && rbase + rg < M) {
                        alpha_s[(size_t)(rbase + rg) * HEADS + head] = s;
                        alpha_d[(size_t)(rbase + rg) * HEADS + head] = d;
                    }
                    ps[rg] = 0.f; pd[rg] = 0.f;
                }
            }
        }
        if constexpr (CPH != 16) {
            const int head = (n0 + wc * WCOLS) / CPH;
#pragma unroll
            for (int rg = 0; rg < 4; ++rg) {
                float s = ps[rg], d = pd[rg];
#pragma unroll
                for (int m = 1; m <= 8; m <<= 1) {
                    s += __shfl_xor(s, m);
                    d += __shfl_xor(d, m);
                }
                if (lrow == 0 && rbase + rg < M) {
                    alpha_s[(size_t)(rbase + rg) * HEADS + head] = s;
                    alpha_d[(size_t)(rbase + rg) * HEADS + head] = d;
                }
            }
        }
    }
}

// ---------------- CSR build ----------------
__global__ void count_kernel(const int* __restrict__ dst, int* __restrict__ counts, int E)
{
    int e = blockIdx.x * 256 + threadIdx.x;
    if (e < E) atomicAdd(&counts[dst[e]], 1);
}

__global__ void scatter_kernel(const int* __restrict__ src, const int* __restrict__ dst,
                               int* __restrict__ cursor, int* __restrict__ csr, int E)
{
    int e = blockIdx.x * 256 + threadIdx.x;
    if (e < E) {
        int d   = dst[e];
        int pos = atomicAdd(&cursor[d], 1);
        csr[pos] = src[e];
    }
}

// ---------------- parallel scan (3 kernels) ----------------
__global__ __launch_bounds__(1024)
void scan_block_kernel(const int* __restrict__ counts, int* __restrict__ excl_out,
                       int* __restrict__ bsum, int n)
{
    __shared__ int wsum[16];
    const int t = threadIdx.x, lane = t & 63, w = t >> 6;
    const int i = blockIdx.x * 1024 + t;
    int v = (i < n) ? counts[i] : 0;
    int x = v;
#pragma unroll
    for (int d = 1; d < 64; d <<= 1) {
        int y = __shfl_up(x, d);
        if (lane >= d) x += y;
    }
    if (lane == 63) wsum[w] = x;
    __syncthreads();
    if (t < 16) {
        int s = wsum[t];
#pragma unroll
        for (int d = 1; d < 16; d <<= 1) {
            int y = __shfl_up(s, d);
            if (t >= d) s += y;
        }
        wsum[t] = s;
    }
    __syncthreads();
    int wbase = (w > 0) ? wsum[w - 1] : 0;
    if (i < n) excl_out[i] = wbase + x - v;
    if (t == 1023) bsum[blockIdx.x] = wsum[15];
}

__global__ void scan_tops_kernel(const int* __restrict__ bsum, int* __restrict__ boff,
                                 int* __restrict__ row_ptr, int nb, int n)
{
    const int t = threadIdx.x;   // 64 threads, one wave
    int v = (t < nb) ? bsum[t] : 0;
    int x = v;
#pragma unroll
    for (int d = 1; d < 64; d <<= 1) {
        int y = __shfl_up(x, d);
        if (t >= d) x += y;
    }
    if (t < nb) boff[t] = x - v;
    if (t == 63) row_ptr[n] = x;
}

__global__ __launch_bounds__(1024)
void scan_add_kernel(const int* __restrict__ boff, int* __restrict__ row_ptr,
                     int* __restrict__ cursor, int n)
{
    const int i = blockIdx.x * 1024 + threadIdx.x;
    if (i < n) {
        int r = row_ptr[i] + boff[blockIdx.x];
        row_ptr[i] = r;
        cursor[i]  = r;
    }
}

// ---------------- GAT softmax + aggregation ----------------
// One wave per destination node. No max-shift (|e| is O(1), far from f32 exp
// limits). CH=256 writes split-bf16 (hi,lo) for the next MFMA GEMM;
// CH=64 writes f32.
template<int CH>
__global__ __launch_bounds__(256)
void gat_agg(const float* __restrict__ h, const float* __restrict__ alpha_s,
             const float* __restrict__ alpha_d, const int* __restrict__ row_ptr,
             const int* __restrict__ csr_src, const float* __restrict__ bias,
             float* __restrict__ out, unsigned short* __restrict__ out_hi,
             unsigned short* __restrict__ out_lo, int n)
{
    __shared__ float wls[4][64 * 5];   // [wave][j*5+h] stride-5: conflict-free
    __shared__ int   sls[4][64];
    const int wid  = threadIdx.x >> 6;
    const int lane = threadIdx.x & 63;
    const int node = blockIdx.x * 4 + wid;
    if (node >= n) return;
    const int head = lane >> 4;
    const int p0 = row_ptr[node], p1 = row_ptr[node + 1];
    const int deg = p1 - p0;

    const float4 asn = *(const float4*)(alpha_s + (size_t)node * 4);
    const float4 adn = *(const float4*)(alpha_d + (size_t)node * 4);
    float4 den = f4exp(f4lrelu(f4add(asn, adn)));   // self-loop term
    const float wse = pickh(den, head);

    float4 acc4 = make_float4(0.f, 0.f, 0.f, 0.f);
    float  acc1 = 0.f;
    if constexpr (CH == 256) {
        float4 hv = *(const float4*)(h + (size_t)node * CH + lane * 4);
        acc4 = make_float4(wse * hv.x, wse * hv.y, wse * hv.z, wse * hv.w);
    } else {
        acc1 = wse * h[(size_t)node * CH + lane];
    }

    for (int ch = 0; ch < deg; ch += 64) {
        const int cnt = min(64, deg - ch);
        float4 w4 = make_float4(0.f, 0.f, 0.f, 0.f);
        int sl = 0;
        if (lane < cnt) {
            sl = csr_src[p0 + ch + lane];
            float4 al = *(const float4*)(alpha_s + (size_t)sl * 4);
            w4 = f4exp(f4lrelu(f4add(al, adn)));
        }
        float4 t = w4;
#pragma unroll
        for (int d = 32; d >= 1; d >>= 1) {
            t.x += __shfl_xor(t.x, d);
            t.y += __shfl_xor(t.y, d);
            t.z += __shfl_xor(t.z, d);
            t.w += __shfl_xor(t.w, d);
        }
        den = f4add(den, t);
        sls[wid][lane] = sl;
        wls[wid][lane * 5 + 0] = w4.x;
        wls[wid][lane * 5 + 1] = w4.y;
        wls[wid][lane * 5 + 2] = w4.z;
        wls[wid][lane * 5 + 3] = w4.w;

        for (int j = 0; j < cnt; ++j) {
            int   sj = sls[wid][j];
            float w  = wls[wid][j * 5 + head];
            if constexpr (CH == 256) {
                float4 hv = *(const float4*)(h + (size_t)sj * CH + lane * 4);
                acc4.x += w * hv.x; acc4.y += w * hv.y;
                acc4.z += w * hv.z; acc4.w += w * hv.w;
            } else {
                acc1 += w * h[(size_t)sj * CH + lane];
            }
        }
    }

    const float invd = 1.0f / (pickh(den, head) + 1e-16f);
    if constexpr (CH == 256) {
        int c0 = lane * 4;
        float o0 = fmaxf(acc4.x * invd + bias[c0 + 0], 0.f);
        float o1 = fmaxf(acc4.y * invd + bias[c0 + 1], 0.f);
        float o2 = fmaxf(acc4.z * invd + bias[c0 + 2], 0.f);
        float o3 = fmaxf(acc4.w * invd + bias[c0 + 3], 0.f);
        unsigned short h0 = bfr(o0), h1 = bfr(o1), h2 = bfr(o2), h3 = bfr(o3);
        unsigned short l0 = bfr(o0 - bf2f(h0)), l1 = bfr(o1 - bf2f(h1));
        unsigned short l2 = bfr(o2 - bf2f(h2)), l3 = bfr(o3 - bf2f(h3));
        *(uint2*)(out_hi + (size_t)node * CH + c0) =
            make_uint2((unsigned)h0 | ((unsigned)h1 << 16), (unsigned)h2 | ((unsigned)h3 << 16));
        *(uint2*)(out_lo + (size_t)node * CH + c0) =
            make_uint2((unsigned)l0 | ((unsigned)l1 << 16), (unsigned)l2 | ((unsigned)l3 << 16));
    } else {
        out[(size_t)node * CH + lane] = fmaxf(acc1 * invd + bias[lane], 0.f);
    }
}

// ---------------- graph boundaries + fused mean-pool/FC ----------------
__global__ void graph_starts_kernel(const int* __restrict__ batch, int* __restrict__ starts,
                                    int n, int ngraphs)
{
    int g = threadIdx.x;
    if (g > ngraphs) return;
    int lo = 0, hi = n;
    while (lo < hi) {
        int mid = (lo + hi) >> 1;
        if (batch[mid] < g) lo = mid + 1; else hi = mid;
    }
    starts[g] = lo;
}

__global__ __launch_bounds__(256)
void pool_fc_kernel(const float* __restrict__ feat, const int* __restrict__ starts,
                    const float* __restrict__ Wfc, const float* __restrict__ bfc,
                    float* __restrict__ out)
{
    __shared__ float4 part[16][16];
    __shared__ float pooled[64];
    const int g = blockIdx.x;
    const int t = threadIdx.x;
    const int q = t & 15, ns = t >> 4;
    const int s0 = starts[g], s1 = starts[g + 1];
    float4 acc = make_float4(0.f, 0.f, 0.f, 0.f);
    for (int i = s0 + ns; i < s1; i += 16)
        acc = f4add(acc, *(const float4*)(feat + (size_t)i * 64 + q * 4));
    part[ns][q] = acc;
    __syncthreads();
    if (t < 16) {
        float4 s = part[0][t];
#pragma unroll
        for (int k = 1; k < 16; ++k) s = f4add(s, part[k][t]);
        float inv = 1.0f / fmaxf((float)(s1 - s0), 1.0f);
        pooled[t * 4 + 0] = s.x * inv;
        pooled[t * 4 + 1] = s.y * inv;
        pooled[t * 4 + 2] = s.z * inv;
        pooled[t * 4 + 3] = s.w * inv;
    }
    __syncthreads();
    if (t < 2) {
        float a = bfc[t];
        for (int c = 0; c < 64; ++c) a += pooled[c] * Wfc[c * 2 + t];
        out[g * 2 + t] = a;
    }
}

// ---------------- launch ----------------
extern "C" void kernel_launch(void* const* d_in, const int* in_sizes, int n_in,
                              void* d_out, int out_size, void* d_ws, size_t ws_size,
                              hipStream_t stream)
{
    const float* x    = (const float*)d_in[0];
    const int*   ei   = (const int*)d_in[1];
    const int*   batch= (const int*)d_in[2];
    const float* W1   = (const float*)d_in[3];
    const float* as1  = (const float*)d_in[4];
    const float* ad1  = (const float*)d_in[5];
    const float* b1   = (const float*)d_in[6];
    const float* W2   = (const float*)d_in[7];
    const float* as2  = (const float*)d_in[8];
    const float* ad2  = (const float*)d_in[9];
    const float* b2   = (const float*)d_in[10];
    const float* Wfc  = (const float*)d_in[11];
    const float* bfc  = (const float*)d_in[12];
    float* out = (float*)d_out;

    const int N = in_sizes[2];          // 50000 nodes
    const int E = in_sizes[1] / 27;     // 400000 edges
    const int F = in_sizes[0] / N;      // 128

    char* ws = (char*)d_ws;
    float*          h1    = (float*)(ws + OFF_H1);
    float*          h2    = (float*)(ws + OFF_H1);
    float*          out2  = (float*)(ws + OFF_OUT2);
    unsigned short* xhi   = (unsigned short*)(ws + OFF_XHI);
    unsigned short* xlo   = (unsigned short*)(ws + OFF_XLO);
    unsigned short* o1hi  = (unsigned short*)(ws + OFF_O1HI);
    unsigned short* o1lo  = (unsigned short*)(ws + OFF_O1LO);
    unsigned short* w1th  = (unsigned short*)(ws + OFF_W1TH);
    unsigned short* w1tl  = (unsigned short*)(ws + OFF_W1TL);
    unsigned short* w2th  = (unsigned short*)(ws + OFF_W2TH);
    unsigned short* w2tl  = (unsigned short*)(ws + OFF_W2TL);
    float* al_s  = (float*)(ws + OFF_AS);
    float* al_d  = (float*)(ws + OFF_AD);
    int*   rp    = (int*)(ws + OFF_RP);
    int*   cur   = (int*)(ws + OFF_CUR);
    int*   cnt   = (int*)(ws + OFF_CNT);
    int*   csr   = (int*)(ws + OFF_CSR);
    int*   strt  = (int*)(ws + OFF_STRT);
    int*   bsum  = (int*)(ws + OFF_BSUM);
    int*   boff  = (int*)(ws + OFF_BOFF);

    const int egrid = (E + 255) / 256;
    const int NB    = (N + 1023) / 1024;   // scan blocks (49)

    // ---- splits ----
    split_kernel<<<2048, 256, 0, stream>>>(x, xhi, xlo, N * F / 4);
    wsplit_kernel<<<(F * HEADS * 64 + 255) / 256, 256, 0, stream>>>(W1, w1th, w1tl, F, HEADS * 64);
    wsplit_kernel<<<(HEADS * 64 * HEADS * 16 + 255) / 256, 256, 0, stream>>>(W2, w2th, w2tl, HEADS * 64, HEADS * 16);

    // ---- layer 1: MFMA GEMM (M=50000, K=128, Ncols=256) ----
    {
        dim3 g((N + 127) / 128, 2);
        mfma_gemm_gat<128, 128, 128, 2, 2, 64><<<g, 256, 0, stream>>>(
            xhi, xlo, w1th, w1tl, h1, as1, ad1, al_s, al_d, N, HEADS * 64);
    }
    hipMemsetAsync(cnt, 0, (size_t)N * sizeof(int), stream);
    count_kernel<<<egrid, 256, 0, stream>>>(ei + 26 * (size_t)E, cnt, E);
    scan_block_kernel<<<NB, 1024, 0, stream>>>(cnt, rp, bsum, N);
    scan_tops_kernel<<<1, 64, 0, stream>>>(bsum, boff, rp, NB, N);
    scan_add_kernel<<<NB, 1024, 0, stream>>>(boff, rp, cur, N);
    scatter_kernel<<<egrid, 256, 0, stream>>>(ei + 17 * (size_t)E, ei + 26 * (size_t)E, cur, csr, E);
    gat_agg<256><<<(N + 3) / 4, 256, 0, stream>>>(h1, al_s, al_d, rp, csr, b1,
                                                  nullptr, o1hi, o1lo, N);

    // ---- layer 2: MFMA GEMM (M=50000, K=256, Ncols=64) ----
    {
        dim3 g((N + 63) / 64, 1);
        mfma_gemm_gat<64, 64, 256, 2, 2, 16><<<g, 256, 0, stream>>>(
            o1hi, o1lo, w2th, w2tl, h2, as2, ad2, al_s, al_d, N, HEADS * 16);
    }
    hipMemsetAsync(cnt, 0, (size_t)N * sizeof(int), stream);
    count_kernel<<<egrid, 256, 0, stream>>>(ei + 16 * (size_t)E, cnt, E);
    scan_block_kernel<<<NB, 1024, 0, stream>>>(cnt, rp, bsum, N);
    scan_tops_kernel<<<1, 64, 0, stream>>>(bsum, boff, rp, NB, N);
    scan_add_kernel<<<NB, 1024, 0, stream>>>(boff, rp, cur, N);
    scatter_kernel<<<egrid, 256, 0, stream>>>(ei + 15 * (size_t)E, ei + 16 * (size_t)E, cur, csr, E);
    gat_agg<64><<<(N + 3) / 4, 256, 0, stream>>>(h2, al_s, al_d, rp, csr, b2,
                                                 out2, nullptr, nullptr, N);

    // ---- pool + fc ----
    graph_starts_kernel<<<1, 65, 0, stream>>>(batch, strt, N, 64);
    pool_fc_kernel<<<64, 256, 0, stream>>>(out2, strt, Wfc, bfc, out);
}

// Round 7
// 250.264 us; speedup vs baseline: 1.6128x; 1.1517x over previous
//
#include <hip/hip_runtime.h>
#include <math.h>

#define HEADS 4
#define NEG_SLOPE 0.2f

// ---------------- workspace layout (bytes) ----------------
// h1b bf16 @0 (25.6M) -> dead after agg1; h2b bf16 @0 (6.4M); out2 f32 @6.4M (12.8M)
// xhi/xlo bf16 @25.6M/38.4M (dead after GEMM1); o1hi/o1lo bf16 @25.6M/51.2M (agg1 out)
static constexpr size_t OFF_H1B  = 0;
static constexpr size_t OFF_H2B  = 0;
static constexpr size_t OFF_OUT2 = 6400000;
static constexpr size_t OFF_XHI  = 25600000;
static constexpr size_t OFF_XLO  = 38400000;
static constexpr size_t OFF_O1HI = 25600000;   // aliases xhi/xlo (dead by then)
static constexpr size_t OFF_O1LO = 51200000;
static constexpr size_t OFF_W1TH = 76800000;   // 256x128 bf16 = 64KB
static constexpr size_t OFF_W1TL = 76865536;
static constexpr size_t OFF_W2TH = 76931072;   // 64x256 bf16 = 32KB
static constexpr size_t OFF_W2TL = 76963840;
static constexpr size_t OFF_AS   = 77000000;   // 800,000
static constexpr size_t OFF_AD   = 77800000;   // 800,000
static constexpr size_t OFF_RP   = 78600064;   // (2N+1) ints = 400,004
static constexpr size_t OFF_CUR  = 79000128;   // 2N ints
static constexpr size_t OFF_CNT  = 79400128;   // 2N ints
static constexpr size_t OFF_CSR  = 79800128;   // 2E ints = 3.2M
static constexpr size_t OFF_STRT = 83000128;   // 65 ints
static constexpr size_t OFF_BSUM = 83000448;   // <=256 ints
static constexpr size_t OFF_BOFF = 83001472;

typedef __attribute__((ext_vector_type(8))) short short8;
typedef __attribute__((ext_vector_type(4))) float f32x4;

// ---------------- helpers ----------------
__device__ __forceinline__ float4 f4add(float4 a, float4 b) {
    return make_float4(a.x + b.x, a.y + b.y, a.z + b.z, a.w + b.w);
}
__device__ __forceinline__ float lrelu(float x) { return x > 0.f ? x : NEG_SLOPE * x; }
__device__ __forceinline__ float4 f4lrelu(float4 a) {
    return make_float4(lrelu(a.x), lrelu(a.y), lrelu(a.z), lrelu(a.w));
}
__device__ __forceinline__ float4 f4exp(float4 a) {
    return make_float4(__expf(a.x), __expf(a.y), __expf(a.z), __expf(a.w));
}
__device__ __forceinline__ float pickh(float4 v, int head) {
    float r = v.x;
    r = head == 1 ? v.y : r;
    r = head == 2 ? v.z : r;
    r = head == 3 ? v.w : r;
    return r;
}
// round-to-nearest bf16 (no NaN in this workload)
__device__ __forceinline__ unsigned short bfr(float x) {
    union { float f; unsigned u; } c; c.f = x;
    unsigned r = c.u + 0x7FFFu + ((c.u >> 16) & 1u);
    return (unsigned short)(r >> 16);
}
__device__ __forceinline__ float bf2f(unsigned short h) {
    union { unsigned u; float f; } c; c.u = ((unsigned)h) << 16;
    return c.f;
}
// unpack packed pair of bf16 (lo = bits[15:0], hi = bits[31:16]) to floats
__device__ __forceinline__ float2 bfpair(unsigned u) {
    union { unsigned a; float f; } lo, hi;
    lo.a = u << 16;
    hi.a = u & 0xffff0000u;
    return make_float2(lo.f, hi.f);
}

// ---------------- split kernels ----------------
__global__ void split_kernel(const float* __restrict__ in, unsigned short* __restrict__ hi,
                             unsigned short* __restrict__ lo, int n4)
{
    int i = blockIdx.x * 256 + threadIdx.x;
    const int stride = gridDim.x * 256;
    for (; i < n4; i += stride) {
        float4 v = ((const float4*)in)[i];
        unsigned short h0 = bfr(v.x), h1 = bfr(v.y), h2 = bfr(v.z), h3 = bfr(v.w);
        unsigned short l0 = bfr(v.x - bf2f(h0)), l1 = bfr(v.y - bf2f(h1));
        unsigned short l2 = bfr(v.z - bf2f(h2)), l3 = bfr(v.w - bf2f(h3));
        ((uint2*)hi)[i] = make_uint2((unsigned)h0 | ((unsigned)h1 << 16),
                                     (unsigned)h2 | ((unsigned)h3 << 16));
        ((uint2*)lo)[i] = make_uint2((unsigned)l0 | ((unsigned)l1 << 16),
                                     (unsigned)l2 | ((unsigned)l3 << 16));
    }
}

// W[K][N] f32 -> WT_hi/lo[N][K] bf16; one thread per element
__global__ void wsplit_kernel(const float* __restrict__ W, unsigned short* __restrict__ hiT,
                              unsigned short* __restrict__ loT, int K, int N)
{
    int idx = blockIdx.x * 256 + threadIdx.x;
    if (idx >= K * N) return;
    int k = idx / N, n = idx - k * N;
    float v = W[idx];
    unsigned short h = bfr(v);
    hiT[(size_t)n * K + k] = h;
    loT[(size_t)n * K + k] = bfr(v - bf2f(h));
}

// ---------------- MFMA GEMM with GAT-alpha epilogue ----------------
// C = A·B via split-bf16 3-pass; C written as bf16. alpha computed from f32 acc.
template<int BM, int BN, int KDIM, int WR, int WC, int CPH>
__global__ __launch_bounds__(256, 2)
void mfma_gemm_gat(const unsigned short* __restrict__ Ahi, const unsigned short* __restrict__ Alo,
                   const unsigned short* __restrict__ BThi, const unsigned short* __restrict__ BTlo,
                   unsigned short* __restrict__ Cb,
                   const float* __restrict__ avec_s, const float* __restrict__ avec_d,
                   float* __restrict__ alpha_s, float* __restrict__ alpha_d,
                   int M, int N)
{
    constexpr int BK    = 32;
    constexpr int WROWS = BM / WR;
    constexpr int WCOLS = BN / WC;
    constexpr int FR    = WROWS / 16;
    constexpr int FC    = WCOLS / 16;
    constexpr int AP    = (BM * (BK / 8)) / 256;
    constexpr int BP    = (BN * (BK / 8)) / 256;
    static_assert(AP >= 1 && BP >= 1, "tile too small");

    __shared__ short As_hi[BM * BK], As_lo[BM * BK];
    __shared__ short Bs_hi[BN * BK], Bs_lo[BN * BK];

    const int tid  = threadIdx.x;
    const int w    = tid >> 6, lane = tid & 63;
    const int wr   = w / WC, wc = w % WC;
    const int lrow = lane & 15, lk = lane >> 4;
    const int m0   = blockIdx.x * BM, n0 = blockIdx.y * BN;

    f32x4 acc[FR][FC];
#pragma unroll
    for (int i = 0; i < FR; ++i)
#pragma unroll
        for (int j = 0; j < FC; ++j) acc[i][j] = (f32x4){0.f, 0.f, 0.f, 0.f};

    short8 rAh[AP], rAl[AP], rBh[BP], rBl[BP];

    auto LOAD = [&](int kb) {
#pragma unroll
        for (int p = 0; p < AP; ++p) {
            int id = p * 256 + tid;
            int r = id >> 2, c = id & 3;
            int row = m0 + r; row = row < M ? row : M - 1;
            size_t off = (size_t)row * KDIM + kb + c * 8;
            rAh[p] = *(const short8*)(Ahi + off);
            rAl[p] = *(const short8*)(Alo + off);
        }
#pragma unroll
        for (int p = 0; p < BP; ++p) {
            int id = p * 256 + tid;
            int r = id >> 2, c = id & 3;
            size_t off = (size_t)(n0 + r) * KDIM + kb + c * 8;
            rBh[p] = *(const short8*)(BThi + off);
            rBl[p] = *(const short8*)(BTlo + off);
        }
    };
    auto STORE = [&]() {
#pragma unroll
        for (int p = 0; p < AP; ++p) {
            int id = p * 256 + tid;
            int r = id >> 2, c = id & 3;
            *(short8*)(&As_hi[r * BK + c * 8]) = rAh[p];
            *(short8*)(&As_lo[r * BK + c * 8]) = rAl[p];
        }
#pragma unroll
        for (int p = 0; p < BP; ++p) {
            int id = p * 256 + tid;
            int r = id >> 2, c = id & 3;
            *(short8*)(&Bs_hi[r * BK + c * 8]) = rBh[p];
            *(short8*)(&Bs_lo[r * BK + c * 8]) = rBl[p];
        }
    };

    constexpr int NT = KDIM / BK;
    LOAD(0);
    for (int t = 0; t < NT; ++t) {
        STORE();
        __syncthreads();
        if (t + 1 < NT) LOAD((t + 1) * BK);

        short8 afh[FR], afl[FR], bfh[FC], bfl[FC];
#pragma unroll
        for (int fr = 0; fr < FR; ++fr) {
            int r = wr * WROWS + fr * 16 + lrow;
            afh[fr] = *(const short8*)(&As_hi[r * BK + lk * 8]);
            afl[fr] = *(const short8*)(&As_lo[r * BK + lk * 8]);
        }
#pragma unroll
        for (int fc = 0; fc < FC; ++fc) {
            int r = wc * WCOLS + fc * 16 + lrow;
            bfh[fc] = *(const short8*)(&Bs_hi[r * BK + lk * 8]);
            bfl[fc] = *(const short8*)(&Bs_lo[r * BK + lk * 8]);
        }
#pragma unroll
        for (int fr = 0; fr < FR; ++fr)
#pragma unroll
            for (int fc = 0; fc < FC; ++fc) {
                acc[fr][fc] = __builtin_amdgcn_mfma_f32_16x16x32_bf16(afh[fr], bfh[fc], acc[fr][fc], 0, 0, 0);
                acc[fr][fc] = __builtin_amdgcn_mfma_f32_16x16x32_bf16(afh[fr], bfl[fc], acc[fr][fc], 0, 0, 0);
                acc[fr][fc] = __builtin_amdgcn_mfma_f32_16x16x32_bf16(afl[fr], bfh[fc], acc[fr][fc], 0, 0, 0);
            }
        __syncthreads();
    }

#pragma unroll
    for (int fr = 0; fr < FR; ++fr) {
        const int rbase = m0 + wr * WROWS + fr * 16 + lk * 4;
        float ps[4] = {0.f, 0.f, 0.f, 0.f}, pd[4] = {0.f, 0.f, 0.f, 0.f};
#pragma unroll
        for (int fc = 0; fc < FC; ++fc) {
            const int gc   = n0 + wc * WCOLS + fc * 16 + lrow;
            const int head = gc / CPH, ci = gc % CPH;
            const float asv = avec_s[head * CPH + ci];
            const float adv = avec_d[head * CPH + ci];
#pragma unroll
            for (int rg = 0; rg < 4; ++rg) {
                int row = rbase + rg;
                float v = acc[fr][fc][rg];
                if (row < M) Cb[(size_t)row * N + gc] = bfr(v);
                ps[rg] += v * asv;
                pd[rg] += v * adv;
            }
            if constexpr (CPH == 16) {
#pragma unroll
                for (int rg = 0; rg < 4; ++rg) {
                    float s = ps[rg], d = pd[rg];
#pragma unroll
                    for (int m = 1; m <= 8; m <<= 1) {
                        s += __shfl_xor(s, m);
                        d += __shfl_xor(d, m);
                    }
                    if (lrow == 0 && rbase + rg < M) {
                        alpha_s[(size_t)(rbase + rg) * HEADS + head] = s;
                        alpha_d[(size_t)(rbase + rg) * HEADS + head] = d;
                    }
                    ps[rg] = 0.f; pd[rg] = 0.f;
                }
            }
        }
        if constexpr (CPH != 16) {
            const int head = (n0 + wc * WCOLS) / CPH;
#pragma unroll
            for (int rg = 0; rg < 4; ++rg) {
                float s = ps[rg], d = pd[rg];
#pragma unroll
                for (int m = 1; m <= 8; m <<= 1) {
                    s += __shfl_xor(s, m);
                    d += __shfl_xor(d, m);
                }
                if (lrow == 0 && rbase + rg < M) {
                    alpha_s[(size_t)(rbase + rg) * HEADS + head] = s;
                    alpha_d[(size_t)(rbase + rg) * HEADS + head] = d;
                }
            }
        }
    }
}

// ---------------- fused 2-layer CSR build ----------------
// counts for both layers in one array: cnt[0..N) layer1, cnt[N..2N) layer2.
__global__ void count2_kernel(const int* __restrict__ dst1, const int* __restrict__ dst2,
                              int* __restrict__ counts, int N, int E)
{
    int e = blockIdx.x * 256 + threadIdx.x;
    if (e < E)            atomicAdd(&counts[dst1[e]], 1);
    else if (e < 2 * E)   atomicAdd(&counts[N + dst2[e - E]], 1);
}

__global__ void scatter2_kernel(const int* __restrict__ src1, const int* __restrict__ dst1,
                                const int* __restrict__ src2, const int* __restrict__ dst2,
                                int* __restrict__ cursor, int* __restrict__ csr, int N, int E)
{
    int e = blockIdx.x * 256 + threadIdx.x;
    if (e < E) {
        int pos = atomicAdd(&cursor[dst1[e]], 1);
        csr[pos] = src1[e];
    } else if (e < 2 * E) {
        int pos = atomicAdd(&cursor[N + dst2[e - E]], 1);
        csr[pos] = src2[e - E];
    }
}

// ---------------- parallel scan (3 kernels) ----------------
__global__ __launch_bounds__(1024)
void scan_block_kernel(const int* __restrict__ counts, int* __restrict__ excl_out,
                       int* __restrict__ bsum, int n)
{
    __shared__ int wsum[16];
    const int t = threadIdx.x, lane = t & 63, w = t >> 6;
    const int i = blockIdx.x * 1024 + t;
    int v = (i < n) ? counts[i] : 0;
    int x = v;
#pragma unroll
    for (int d = 1; d < 64; d <<= 1) {
        int y = __shfl_up(x, d);
        if (lane >= d) x += y;
    }
    if (lane == 63) wsum[w] = x;
    __syncthreads();
    if (t < 16) {
        int s = wsum[t];
#pragma unroll
        for (int d = 1; d < 16; d <<= 1) {
            int y = __shfl_up(s, d);
            if (t >= d) s += y;
        }
        wsum[t] = s;
    }
    __syncthreads();
    int wbase = (w > 0) ? wsum[w - 1] : 0;
    if (i < n) excl_out[i] = wbase + x - v;
    if (t == 1023) bsum[blockIdx.x] = wsum[15];
}

// 1 block, 256 threads: scan of up to 256 block totals; writes row_ptr[ntot]=grand total
__global__ __launch_bounds__(256)
void scan_tops_kernel(const int* __restrict__ bsum, int* __restrict__ boff,
                      int* __restrict__ row_ptr, int nb, int ntot)
{
    __shared__ int wtot[4];
    const int t = threadIdx.x, lane = t & 63, w = t >> 6;
    int v = (t < nb) ? bsum[t] : 0;
    int x = v;
#pragma unroll
    for (int d = 1; d < 64; d <<= 1) {
        int y = __shfl_up(x, d);
        if (lane >= d) x += y;
    }
    if (lane == 63) wtot[w] = x;
    __syncthreads();
    int wbase = 0;
    for (int k = 0; k < w; ++k) wbase += wtot[k];
    if (t < nb) boff[t] = wbase + x - v;
    if (t == 255) row_ptr[ntot] = wbase + x;
}

__global__ __launch_bounds__(1024)
void scan_add_kernel(const int* __restrict__ boff, int* __restrict__ row_ptr,
                     int* __restrict__ cursor, int n)
{
    const int i = blockIdx.x * 1024 + threadIdx.x;
    if (i < n) {
        int r = row_ptr[i] + boff[blockIdx.x];
        row_ptr[i] = r;
        cursor[i]  = r;
    }
}

// ---------------- GAT softmax + aggregation (bf16 h gather) ----------------
// One wave per destination node. No max-shift (|e| is O(1), far from f32 exp limits).
// h rows are bf16: CH=256 -> 512B/row (uint2/lane), CH=64 -> 128B/row (ushort/lane).
template<int CH>
__global__ __launch_bounds__(256)
void gat_agg(const unsigned short* __restrict__ hb, const float* __restrict__ alpha_s,
             const float* __restrict__ alpha_d, const int* __restrict__ row_ptr,
             const int* __restrict__ csr_src, const float* __restrict__ bias,
             float* __restrict__ out, unsigned short* __restrict__ out_hi,
             unsigned short* __restrict__ out_lo, int n)
{
    __shared__ float wls[4][64 * 5];   // [wave][j*5+h] stride-5: conflict-free
    __shared__ int   sls[4][64];
    const int wid  = threadIdx.x >> 6;
    const int lane = threadIdx.x & 63;
    const int node = blockIdx.x * 4 + wid;
    if (node >= n) return;
    const int head = lane >> 4;
    const int p0 = row_ptr[node], p1 = row_ptr[node + 1];
    const int deg = p1 - p0;

    const float4 asn = *(const float4*)(alpha_s + (size_t)node * 4);
    const float4 adn = *(const float4*)(alpha_d + (size_t)node * 4);
    float4 den = f4exp(f4lrelu(f4add(asn, adn)));   // self-loop term
    const float wse = pickh(den, head);

    float4 acc4 = make_float4(0.f, 0.f, 0.f, 0.f);
    float  acc1 = 0.f;
    if constexpr (CH == 256) {
        uint2 hv = *(const uint2*)(hb + (size_t)node * CH + lane * 4);
        float2 q0 = bfpair(hv.x), q1 = bfpair(hv.y);
        acc4 = make_float4(wse * q0.x, wse * q0.y, wse * q1.x, wse * q1.y);
    } else {
        acc1 = wse * bf2f(hb[(size_t)node * CH + lane]);
    }

    for (int ch = 0; ch < deg; ch += 64) {
        const int cnt = min(64, deg - ch);
        float4 w4 = make_float4(0.f, 0.f, 0.f, 0.f);
        int sl = 0;
        if (lane < cnt) {
            sl = csr_src[p0 + ch + lane];
            float4 al = *(const float4*)(alpha_s + (size_t)sl * 4);
            w4 = f4exp(f4lrelu(f4add(al, adn)));
        }
        float4 t = w4;
#pragma unroll
        for (int d = 32; d >= 1; d >>= 1) {
            t.x += __shfl_xor(t.x, d);
            t.y += __shfl_xor(t.y, d);
            t.z += __shfl_xor(t.z, d);
            t.w += __shfl_xor(t.w, d);
        }
        den = f4add(den, t);
        sls[wid][lane] = sl;
        wls[wid][lane * 5 + 0] = w4.x;
        wls[wid][lane * 5 + 1] = w4.y;
        wls[wid][lane * 5 + 2] = w4.z;
        wls[wid][lane * 5 + 3] = w4.w;

        for (int j = 0; j < cnt; ++j) {
            int   sj = sls[wid][j];
            float w  = wls[wid][j * 5 + head];
            if constexpr (CH == 256) {
                uint2 hv = *(const uint2*)(hb + (size_t)sj * CH + lane * 4);
                float2 q0 = bfpair(hv.x), q1 = bfpair(hv.y);
                acc4.x += w * q0.x; acc4.y += w * q0.y;
                acc4.z += w * q1.x; acc4.w += w * q1.y;
            } else {
                acc1 += w * bf2f(hb[(size_t)sj * CH + lane]);
            }
        }
    }

    const float invd = 1.0f / (pickh(den, head) + 1e-16f);
    if constexpr (CH == 256) {
        int c0 = lane * 4;
        float o0 = fmaxf(acc4.x * invd + bias[c0 + 0], 0.f);
        float o1 = fmaxf(acc4.y * invd + bias[c0 + 1], 0.f);
        float o2 = fmaxf(acc4.z * invd + bias[c0 + 2], 0.f);
        float o3 = fmaxf(acc4.w * invd + bias[c0 + 3], 0.f);
        unsigned short h0 = bfr(o0), h1 = bfr(o1), h2 = bfr(o2), h3 = bfr(o3);
        unsigned short l0 = bfr(o0 - bf2f(h0)), l1 = bfr(o1 - bf2f(h1));
        unsigned short l2 = bfr(o2 - bf2f(h2)), l3 = bfr(o3 - bf2f(h3));
        *(uint2*)(out_hi + (size_t)node * CH + c0) =
            make_uint2((unsigned)h0 | ((unsigned)h1 << 16), (unsigned)h2 | ((unsigned)h3 << 16));
        *(uint2*)(out_lo + (size_t)node * CH + c0) =
            make_uint2((unsigned)l0 | ((unsigned)l1 << 16), (unsigned)l2 | ((unsigned)l3 << 16));
    } else {
        out[(size_t)node * CH + lane] = fmaxf(acc1 * invd + bias[lane], 0.f);
    }
}

// ---------------- graph boundaries + fused mean-pool/FC ----------------
__global__ void graph_starts_kernel(const int* __restrict__ batch, int* __restrict__ starts,
                                    int n, int ngraphs)
{
    int g = threadIdx.x;
    if (g > ngraphs) return;
    int lo = 0, hi = n;
    while (lo < hi) {
        int mid = (lo + hi) >> 1;
        if (batch[mid] < g) lo = mid + 1; else hi = mid;
    }
    starts[g] = lo;
}

__global__ __launch_bounds__(256)
void pool_fc_kernel(const float* __restrict__ feat, const int* __restrict__ starts,
                    const float* __restrict__ Wfc, const float* __restrict__ bfc,
                    float* __restrict__ out)
{
    __shared__ float4 part[16][16];
    __shared__ float pooled[64];
    const int g = blockIdx.x;
    const int t = threadIdx.x;
    const int q = t & 15, ns = t >> 4;
    const int s0 = starts[g], s1 = starts[g + 1];
    float4 acc = make_float4(0.f, 0.f, 0.f, 0.f);
    for (int i = s0 + ns; i < s1; i += 16)
        acc = f4add(acc, *(const float4*)(feat + (size_t)i * 64 + q * 4));
    part[ns][q] = acc;
    __syncthreads();
    if (t < 16) {
        float4 s = part[0][t];
#pragma unroll
        for (int k = 1; k < 16; ++k) s = f4add(s, part[k][t]);
        float inv = 1.0f / fmaxf((float)(s1 - s0), 1.0f);
        pooled[t * 4 + 0] = s.x * inv;
        pooled[t * 4 + 1] = s.y * inv;
        pooled[t * 4 + 2] = s.z * inv;
        pooled[t * 4 + 3] = s.w * inv;
    }
    __syncthreads();
    if (t < 2) {
        float a = bfc[t];
        for (int c = 0; c < 64; ++c) a += pooled[c] * Wfc[c * 2 + t];
        out[g * 2 + t] = a;
    }
}

// ---------------- launch ----------------
extern "C" void kernel_launch(void* const* d_in, const int* in_sizes, int n_in,
                              void* d_out, int out_size, void* d_ws, size_t ws_size,
                              hipStream_t stream)
{
    const float* x    = (const float*)d_in[0];
    const int*   ei   = (const int*)d_in[1];
    const int*   batch= (const int*)d_in[2];
    const float* W1   = (const float*)d_in[3];
    const float* as1  = (const float*)d_in[4];
    const float* ad1  = (const float*)d_in[5];
    const float* b1   = (const float*)d_in[6];
    const float* W2   = (const float*)d_in[7];
    const float* as2  = (const float*)d_in[8];
    const float* ad2  = (const float*)d_in[9];
    const float* b2   = (const float*)d_in[10];
    const float* Wfc  = (const float*)d_in[11];
    const float* bfc  = (const float*)d_in[12];
    float* out = (float*)d_out;

    const int N = in_sizes[2];          // 50000 nodes
    const int E = in_sizes[1] / 27;     // 400000 edges
    const int F = in_sizes[0] / N;      // 128

    char* ws = (char*)d_ws;
    unsigned short* h1b   = (unsigned short*)(ws + OFF_H1B);
    unsigned short* h2b   = (unsigned short*)(ws + OFF_H2B);
    float*          out2  = (float*)(ws + OFF_OUT2);
    unsigned short* xhi   = (unsigned short*)(ws + OFF_XHI);
    unsigned short* xlo   = (unsigned short*)(ws + OFF_XLO);
    unsigned short* o1hi  = (unsigned short*)(ws + OFF_O1HI);
    unsigned short* o1lo  = (unsigned short*)(ws + OFF_O1LO);
    unsigned short* w1th  = (unsigned short*)(ws + OFF_W1TH);
    unsigned short* w1tl  = (unsigned short*)(ws + OFF_W1TL);
    unsigned short* w2th  = (unsigned short*)(ws + OFF_W2TH);
    unsigned short* w2tl  = (unsigned short*)(ws + OFF_W2TL);
    float* al_s  = (float*)(ws + OFF_AS);
    float* al_d  = (float*)(ws + OFF_AD);
    int*   rp    = (int*)(ws + OFF_RP);     // (2N+1) entries; layer2 view = rp+N
    int*   cur   = (int*)(ws + OFF_CUR);    // 2N
    int*   cnt   = (int*)(ws + OFF_CNT);    // 2N
    int*   csr   = (int*)(ws + OFF_CSR);    // 2E (global positions)
    int*   strt  = (int*)(ws + OFF_STRT);
    int*   bsum  = (int*)(ws + OFF_BSUM);
    int*   boff  = (int*)(ws + OFF_BOFF);

    const int e2grid = (2 * E + 255) / 256;
    const int NB2    = (2 * N + 1023) / 1024;   // 98 blocks

    // ---- splits ----
    split_kernel<<<2048, 256, 0, stream>>>(x, xhi, xlo, N * F / 4);
    wsplit_kernel<<<(F * HEADS * 64 + 255) / 256, 256, 0, stream>>>(W1, w1th, w1tl, F, HEADS * 64);
    wsplit_kernel<<<(HEADS * 64 * HEADS * 16 + 255) / 256, 256, 0, stream>>>(W2, w2th, w2tl, HEADS * 64, HEADS * 16);

    // ---- fused CSR build for both layers ----
    hipMemsetAsync(cnt, 0, (size_t)2 * N * sizeof(int), stream);
    count2_kernel<<<e2grid, 256, 0, stream>>>(ei + 26 * (size_t)E, ei + 16 * (size_t)E, cnt, N, E);
    scan_block_kernel<<<NB2, 1024, 0, stream>>>(cnt, rp, bsum, 2 * N);
    scan_tops_kernel<<<1, 256, 0, stream>>>(bsum, boff, rp, NB2, 2 * N);
    scan_add_kernel<<<NB2, 1024, 0, stream>>>(boff, rp, cur, 2 * N);
    scatter2_kernel<<<e2grid, 256, 0, stream>>>(ei + 17 * (size_t)E, ei + 26 * (size_t)E,
                                                ei + 15 * (size_t)E, ei + 16 * (size_t)E,
                                                cur, csr, N, E);

    // ---- layer 1: MFMA GEMM (M=50000, K=128, Ncols=256) -> bf16 h1 ----
    {
        dim3 g((N + 127) / 128, 2);
        mfma_gemm_gat<128, 128, 128, 2, 2, 64><<<g, 256, 0, stream>>>(
            xhi, xlo, w1th, w1tl, h1b, as1, ad1, al_s, al_d, N, HEADS * 64);
    }
    gat_agg<256><<<(N + 3) / 4, 256, 0, stream>>>(h1b, al_s, al_d, rp, csr, b1,
                                                  nullptr, o1hi, o1lo, N);

    // ---- layer 2: MFMA GEMM (M=50000, K=256, Ncols=64) -> bf16 h2 ----
    {
        dim3 g((N + 63) / 64, 1);
        mfma_gemm_gat<64, 64, 256, 2, 2, 16><<<g, 256, 0, stream>>>(
            o1hi, o1lo, w2th, w2tl, h2b, as2, ad2, al_s, al_d, N, HEADS * 16);
    }
    gat_agg<64><<<(N + 3) / 4, 256, 0, stream>>>(h2b, al_s, al_d, rp + N, csr, b2,
                                                 out2, nullptr, nullptr, N);

    // ---- pool + fc ----
    graph_starts_kernel<<<1, 65, 0, stream>>>(batch, strt, N, 64);
    pool_fc_kernel<<<64, 256, 0, stream>>>(out2, strt, Wfc, bfc, out);
}

// Round 8
// 239.678 us; speedup vs baseline: 1.6841x; 1.0442x over previous
//
#include <hip/hip_runtime.h>
#include <math.h>

#define HEADS 4
#define NEG_SLOPE 0.2f

// ---------------- workspace layout (bytes) ----------------
// h1b bf16 @0 (25.6M) -> dead after agg1; h2b bf16 @0 (6.4M); out2 f32 @6.4M (12.8M)
// xhi/xlo bf16 @25.6M/38.4M (dead after GEMM1); o1hi/o1lo bf16 @25.6M/51.2M (agg1 out)
static constexpr size_t OFF_H1B  = 0;
static constexpr size_t OFF_H2B  = 0;
static constexpr size_t OFF_OUT2 = 6400000;
static constexpr size_t OFF_XHI  = 25600000;
static constexpr size_t OFF_XLO  = 38400000;
static constexpr size_t OFF_O1HI = 25600000;   // aliases xhi/xlo (dead by then)
static constexpr size_t OFF_O1LO = 51200000;
static constexpr size_t OFF_W1TH = 76800000;   // 256x128 bf16 = 64KB
static constexpr size_t OFF_W1TL = 76865536;
static constexpr size_t OFF_W2TH = 76931072;   // 64x256 bf16 = 32KB
static constexpr size_t OFF_W2TL = 76963840;
static constexpr size_t OFF_AS   = 77000000;   // 800,000
static constexpr size_t OFF_AD   = 77800000;   // 800,000
static constexpr size_t OFF_RP   = 78600064;   // (2N+1) ints = 400,004
static constexpr size_t OFF_CUR  = 79000128;   // 2N ints
static constexpr size_t OFF_CNT  = 79400128;   // 2N ints
static constexpr size_t OFF_CSR  = 79800128;   // 2E ints = 3.2M
static constexpr size_t OFF_STRT = 83000128;   // 65 ints
static constexpr size_t OFF_BSUM = 83000448;   // <=256 ints
static constexpr size_t OFF_BOFF = 83001472;

typedef __attribute__((ext_vector_type(8))) short short8;
typedef __attribute__((ext_vector_type(4))) float f32x4;

// ---------------- helpers ----------------
__device__ __forceinline__ float4 f4add(float4 a, float4 b) {
    return make_float4(a.x + b.x, a.y + b.y, a.z + b.z, a.w + b.w);
}
__device__ __forceinline__ float lrelu(float x) { return x > 0.f ? x : NEG_SLOPE * x; }
__device__ __forceinline__ float4 f4lrelu(float4 a) {
    return make_float4(lrelu(a.x), lrelu(a.y), lrelu(a.z), lrelu(a.w));
}
__device__ __forceinline__ float4 f4exp(float4 a) {
    return make_float4(__expf(a.x), __expf(a.y), __expf(a.z), __expf(a.w));
}
__device__ __forceinline__ float pickh(float4 v, int head) {
    float r = v.x;
    r = head == 1 ? v.y : r;
    r = head == 2 ? v.z : r;
    r = head == 3 ? v.w : r;
    return r;
}
// round-to-nearest bf16 (no NaN in this workload)
__device__ __forceinline__ unsigned short bfr(float x) {
    union { float f; unsigned u; } c; c.f = x;
    unsigned r = c.u + 0x7FFFu + ((c.u >> 16) & 1u);
    return (unsigned short)(r >> 16);
}
__device__ __forceinline__ float bf2f(unsigned short h) {
    union { unsigned u; float f; } c; c.u = ((unsigned)h) << 16;
    return c.f;
}
// unpack packed pair of bf16 (lo = bits[15:0], hi = bits[31:16]) to floats
__device__ __forceinline__ float2 bfpair(unsigned u) {
    union { unsigned a; float f; } lo, hi;
    lo.a = u << 16;
    hi.a = u & 0xffff0000u;
    return make_float2(lo.f, hi.f);
}

// ---------------- split kernels ----------------
__global__ void split_kernel(const float* __restrict__ in, unsigned short* __restrict__ hi,
                             unsigned short* __restrict__ lo, int n4)
{
    int i = blockIdx.x * 256 + threadIdx.x;
    const int stride = gridDim.x * 256;
    for (; i < n4; i += stride) {
        float4 v = ((const float4*)in)[i];
        unsigned short h0 = bfr(v.x), h1 = bfr(v.y), h2 = bfr(v.z), h3 = bfr(v.w);
        unsigned short l0 = bfr(v.x - bf2f(h0)), l1 = bfr(v.y - bf2f(h1));
        unsigned short l2 = bfr(v.z - bf2f(h2)), l3 = bfr(v.w - bf2f(h3));
        ((uint2*)hi)[i] = make_uint2((unsigned)h0 | ((unsigned)h1 << 16),
                                     (unsigned)h2 | ((unsigned)h3 << 16));
        ((uint2*)lo)[i] = make_uint2((unsigned)l0 | ((unsigned)l1 << 16),
                                     (unsigned)l2 | ((unsigned)l3 << 16));
    }
}

// W[K][N] f32 -> WT_hi/lo[N][K] bf16; one thread per element
__global__ void wsplit_kernel(const float* __restrict__ W, unsigned short* __restrict__ hiT,
                              unsigned short* __restrict__ loT, int K, int N)
{
    int idx = blockIdx.x * 256 + threadIdx.x;
    if (idx >= K * N) return;
    int k = idx / N, n = idx - k * N;
    float v = W[idx];
    unsigned short h = bfr(v);
    hiT[(size_t)n * K + k] = h;
    loT[(size_t)n * K + k] = bfr(v - bf2f(h));
}

// ---------------- MFMA GEMM with GAT-alpha epilogue ----------------
// C = A·B via split-bf16 3-pass; C written as bf16. alpha computed from f32 acc.
template<int BM, int BN, int KDIM, int WR, int WC, int CPH>
__global__ __launch_bounds__(256, 2)
void mfma_gemm_gat(const unsigned short* __restrict__ Ahi, const unsigned short* __restrict__ Alo,
                   const unsigned short* __restrict__ BThi, const unsigned short* __restrict__ BTlo,
                   unsigned short* __restrict__ Cb,
                   const float* __restrict__ avec_s, const float* __restrict__ avec_d,
                   float* __restrict__ alpha_s, float* __restrict__ alpha_d,
                   int M, int N)
{
    constexpr int BK    = 32;
    constexpr int WROWS = BM / WR;
    constexpr int WCOLS = BN / WC;
    constexpr int FR    = WROWS / 16;
    constexpr int FC    = WCOLS / 16;
    constexpr int AP    = (BM * (BK / 8)) / 256;
    constexpr int BP    = (BN * (BK / 8)) / 256;
    static_assert(AP >= 1 && BP >= 1, "tile too small");

    __shared__ short As_hi[BM * BK], As_lo[BM * BK];
    __shared__ short Bs_hi[BN * BK], Bs_lo[BN * BK];

    const int tid  = threadIdx.x;
    const int w    = tid >> 6, lane = tid & 63;
    const int wr   = w / WC, wc = w % WC;
    const int lrow = lane & 15, lk = lane >> 4;
    const int m0   = blockIdx.x * BM, n0 = blockIdx.y * BN;

    f32x4 acc[FR][FC];
#pragma unroll
    for (int i = 0; i < FR; ++i)
#pragma unroll
        for (int j = 0; j < FC; ++j) acc[i][j] = (f32x4){0.f, 0.f, 0.f, 0.f};

    short8 rAh[AP], rAl[AP], rBh[BP], rBl[BP];

    auto LOAD = [&](int kb) {
#pragma unroll
        for (int p = 0; p < AP; ++p) {
            int id = p * 256 + tid;
            int r = id >> 2, c = id & 3;
            int row = m0 + r; row = row < M ? row : M - 1;
            size_t off = (size_t)row * KDIM + kb + c * 8;
            rAh[p] = *(const short8*)(Ahi + off);
            rAl[p] = *(const short8*)(Alo + off);
        }
#pragma unroll
        for (int p = 0; p < BP; ++p) {
            int id = p * 256 + tid;
            int r = id >> 2, c = id & 3;
            size_t off = (size_t)(n0 + r) * KDIM + kb + c * 8;
            rBh[p] = *(const short8*)(BThi + off);
            rBl[p] = *(const short8*)(BTlo + off);
        }
    };
    auto STORE = [&]() {
#pragma unroll
        for (int p = 0; p < AP; ++p) {
            int id = p * 256 + tid;
            int r = id >> 2, c = id & 3;
            *(short8*)(&As_hi[r * BK + c * 8]) = rAh[p];
            *(short8*)(&As_lo[r * BK + c * 8]) = rAl[p];
        }
#pragma unroll
        for (int p = 0; p < BP; ++p) {
            int id = p * 256 + tid;
            int r = id >> 2, c = id & 3;
            *(short8*)(&Bs_hi[r * BK + c * 8]) = rBh[p];
            *(short8*)(&Bs_lo[r * BK + c * 8]) = rBl[p];
        }
    };

    constexpr int NT = KDIM / BK;
    LOAD(0);
    for (int t = 0; t < NT; ++t) {
        STORE();
        __syncthreads();
        if (t + 1 < NT) LOAD((t + 1) * BK);

        short8 afh[FR], afl[FR], bfh[FC], bfl[FC];
#pragma unroll
        for (int fr = 0; fr < FR; ++fr) {
            int r = wr * WROWS + fr * 16 + lrow;
            afh[fr] = *(const short8*)(&As_hi[r * BK + lk * 8]);
            afl[fr] = *(const short8*)(&As_lo[r * BK + lk * 8]);
        }
#pragma unroll
        for (int fc = 0; fc < FC; ++fc) {
            int r = wc * WCOLS + fc * 16 + lrow;
            bfh[fc] = *(const short8*)(&Bs_hi[r * BK + lk * 8]);
            bfl[fc] = *(const short8*)(&Bs_lo[r * BK + lk * 8]);
        }
#pragma unroll
        for (int fr = 0; fr < FR; ++fr)
#pragma unroll
            for (int fc = 0; fc < FC; ++fc) {
                acc[fr][fc] = __builtin_amdgcn_mfma_f32_16x16x32_bf16(afh[fr], bfh[fc], acc[fr][fc], 0, 0, 0);
                acc[fr][fc] = __builtin_amdgcn_mfma_f32_16x16x32_bf16(afh[fr], bfl[fc], acc[fr][fc], 0, 0, 0);
                acc[fr][fc] = __builtin_amdgcn_mfma_f32_16x16x32_bf16(afl[fr], bfh[fc], acc[fr][fc], 0, 0, 0);
            }
        __syncthreads();
    }

#pragma unroll
    for (int fr = 0; fr < FR; ++fr) {
        const int rbase = m0 + wr * WROWS + fr * 16 + lk * 4;
        float ps[4] = {0.f, 0.f, 0.f, 0.f}, pd[4] = {0.f, 0.f, 0.f, 0.f};
#pragma unroll
        for (int fc = 0; fc < FC; ++fc) {
            const int gc   = n0 + wc * WCOLS + fc * 16 + lrow;
            const int head = gc / CPH, ci = gc % CPH;
            const float asv = avec_s[head * CPH + ci];
            const float adv = avec_d[head * CPH + ci];
#pragma unroll
            for (int rg = 0; rg < 4; ++rg) {
                int row = rbase + rg;
                float v = acc[fr][fc][rg];
                if (row < M) Cb[(size_t)row * N + gc] = bfr(v);
                ps[rg] += v * asv;
                pd[rg] += v * adv;
            }
            if constexpr (CPH == 16) {
#pragma unroll
                for (int rg = 0; rg < 4; ++rg) {
                    float s = ps[rg], d = pd[rg];
#pragma unroll
                    for (int m = 1; m <= 8; m <<= 1) {
                        s += __shfl_xor(s, m);
                        d += __shfl_xor(d, m);
                    }
                    if (lrow == 0 && rbase + rg < M) {
                        alpha_s[(size_t)(rbase + rg) * HEADS + head] = s;
                        alpha_d[(size_t)(rbase + rg) * HEADS + head] = d;
                    }
                    ps[rg] = 0.f; pd[rg] = 0.f;
                }
            }
        }
        if constexpr (CPH != 16) {
            const int head = (n0 + wc * WCOLS) / CPH;
#pragma unroll
            for (int rg = 0; rg < 4; ++rg) {
                float s = ps[rg], d = pd[rg];
#pragma unroll
                for (int m = 1; m <= 8; m <<= 1) {
                    s += __shfl_xor(s, m);
                    d += __shfl_xor(d, m);
                }
                if (lrow == 0 && rbase + rg < M) {
                    alpha_s[(size_t)(rbase + rg) * HEADS + head] = s;
                    alpha_d[(size_t)(rbase + rg) * HEADS + head] = d;
                }
            }
        }
    }
}

// ---------------- fused 2-layer CSR build ----------------
__global__ void count2_kernel(const int* __restrict__ dst1, const int* __restrict__ dst2,
                              int* __restrict__ counts, int N, int E)
{
    int e = blockIdx.x * 256 + threadIdx.x;
    if (e < E)            atomicAdd(&counts[dst1[e]], 1);
    else if (e < 2 * E)   atomicAdd(&counts[N + dst2[e - E]], 1);
}

__global__ void scatter2_kernel(const int* __restrict__ src1, const int* __restrict__ dst1,
                                const int* __restrict__ src2, const int* __restrict__ dst2,
                                int* __restrict__ cursor, int* __restrict__ csr, int N, int E)
{
    int e = blockIdx.x * 256 + threadIdx.x;
    if (e < E) {
        int pos = atomicAdd(&cursor[dst1[e]], 1);
        csr[pos] = src1[e];
    } else if (e < 2 * E) {
        int pos = atomicAdd(&cursor[N + dst2[e - E]], 1);
        csr[pos] = src2[e - E];
    }
}

// ---------------- parallel scan (3 kernels) ----------------
__global__ __launch_bounds__(1024)
void scan_block_kernel(const int* __restrict__ counts, int* __restrict__ excl_out,
                       int* __restrict__ bsum, int n)
{
    __shared__ int wsum[16];
    const int t = threadIdx.x, lane = t & 63, w = t >> 6;
    const int i = blockIdx.x * 1024 + t;
    int v = (i < n) ? counts[i] : 0;
    int x = v;
#pragma unroll
    for (int d = 1; d < 64; d <<= 1) {
        int y = __shfl_up(x, d);
        if (lane >= d) x += y;
    }
    if (lane == 63) wsum[w] = x;
    __syncthreads();
    if (t < 16) {
        int s = wsum[t];
#pragma unroll
        for (int d = 1; d < 16; d <<= 1) {
            int y = __shfl_up(s, d);
            if (t >= d) s += y;
        }
        wsum[t] = s;
    }
    __syncthreads();
    int wbase = (w > 0) ? wsum[w - 1] : 0;
    if (i < n) excl_out[i] = wbase + x - v;
    if (t == 1023) bsum[blockIdx.x] = wsum[15];
}

__global__ __launch_bounds__(256)
void scan_tops_kernel(const int* __restrict__ bsum, int* __restrict__ boff,
                      int* __restrict__ row_ptr, int nb, int ntot)
{
    __shared__ int wtot[4];
    const int t = threadIdx.x, lane = t & 63, w = t >> 6;
    int v = (t < nb) ? bsum[t] : 0;
    int x = v;
#pragma unroll
    for (int d = 1; d < 64; d <<= 1) {
        int y = __shfl_up(x, d);
        if (lane >= d) x += y;
    }
    if (lane == 63) wtot[w] = x;
    __syncthreads();
    int wbase = 0;
    for (int k = 0; k < w; ++k) wbase += wtot[k];
    if (t < nb) boff[t] = wbase + x - v;
    if (t == 255) row_ptr[ntot] = wbase + x;
}

__global__ __launch_bounds__(1024)
void scan_add_kernel(const int* __restrict__ boff, int* __restrict__ row_ptr,
                     int* __restrict__ cursor, int n)
{
    const int i = blockIdx.x * 1024 + threadIdx.x;
    if (i < n) {
        int r = row_ptr[i] + boff[blockIdx.x];
        row_ptr[i] = r;
        cursor[i]  = r;
    }
}

// ---------------- GAT softmax + aggregation (bf16 h gather, 4-way MLP unroll) ----
// One wave per destination node. No max-shift (|e| is O(1), far from f32 exp limits).
// Inner loop 4-way unrolled: src ids via __shfl broadcast (register, no LDS
// round-trip), 4 independent gather loads in flight -> 4x memory-level parallelism.
template<int CH>
__global__ __launch_bounds__(256)
void gat_agg(const unsigned short* __restrict__ hb, const float* __restrict__ alpha_s,
             const float* __restrict__ alpha_d, const int* __restrict__ row_ptr,
             const int* __restrict__ csr_src, const float* __restrict__ bias,
             float* __restrict__ out, unsigned short* __restrict__ out_hi,
             unsigned short* __restrict__ out_lo, int n)
{
    __shared__ float wls[4][64 * 5];   // [wave][j*5+h] stride-5: conflict-free
    const int wid  = threadIdx.x >> 6;
    const int lane = threadIdx.x & 63;
    const int node = blockIdx.x * 4 + wid;
    if (node >= n) return;
    const int head = lane >> 4;
    const int p0 = row_ptr[node], p1 = row_ptr[node + 1];
    const int deg = p1 - p0;

    const float4 asn = *(const float4*)(alpha_s + (size_t)node * 4);
    const float4 adn = *(const float4*)(alpha_d + (size_t)node * 4);
    float4 den = f4exp(f4lrelu(f4add(asn, adn)));   // self-loop term
    const float wse = pickh(den, head);

    float4 acc4 = make_float4(0.f, 0.f, 0.f, 0.f);
    float  acc1 = 0.f;
    if constexpr (CH == 256) {
        uint2 hv = *(const uint2*)(hb + (size_t)node * CH + lane * 4);
        float2 q0 = bfpair(hv.x), q1 = bfpair(hv.y);
        acc4 = make_float4(wse * q0.x, wse * q0.y, wse * q1.x, wse * q1.y);
    } else {
        acc1 = wse * bf2f(hb[(size_t)node * CH + lane]);
    }

    for (int ch = 0; ch < deg; ch += 64) {
        const int cnt = min(64, deg - ch);
        float4 w4 = make_float4(0.f, 0.f, 0.f, 0.f);
        int sl = 0;
        if (lane < cnt) {
            sl = csr_src[p0 + ch + lane];
            float4 al = *(const float4*)(alpha_s + (size_t)sl * 4);
            w4 = f4exp(f4lrelu(f4add(al, adn)));
        }
        float4 t = w4;
#pragma unroll
        for (int d = 32; d >= 1; d >>= 1) {
            t.x += __shfl_xor(t.x, d);
            t.y += __shfl_xor(t.y, d);
            t.z += __shfl_xor(t.z, d);
            t.w += __shfl_xor(t.w, d);
        }
        den = f4add(den, t);
        wls[wid][lane * 5 + 0] = w4.x;
        wls[wid][lane * 5 + 1] = w4.y;
        wls[wid][lane * 5 + 2] = w4.z;
        wls[wid][lane * 5 + 3] = w4.w;

        int j = 0;
        for (; j + 3 < cnt; j += 4) {
            int s0 = __shfl(sl, j + 0);
            int s1 = __shfl(sl, j + 1);
            int s2 = __shfl(sl, j + 2);
            int s3 = __shfl(sl, j + 3);
            float w0 = wls[wid][(j + 0) * 5 + head];
            float w1 = wls[wid][(j + 1) * 5 + head];
            float w2 = wls[wid][(j + 2) * 5 + head];
            float w3 = wls[wid][(j + 3) * 5 + head];
            if constexpr (CH == 256) {
                uint2 v0 = *(const uint2*)(hb + (size_t)s0 * CH + lane * 4);
                uint2 v1 = *(const uint2*)(hb + (size_t)s1 * CH + lane * 4);
                uint2 v2 = *(const uint2*)(hb + (size_t)s2 * CH + lane * 4);
                uint2 v3 = *(const uint2*)(hb + (size_t)s3 * CH + lane * 4);
                float2 a0 = bfpair(v0.x), b0 = bfpair(v0.y);
                float2 a1 = bfpair(v1.x), b1 = bfpair(v1.y);
                float2 a2 = bfpair(v2.x), b2 = bfpair(v2.y);
                float2 a3 = bfpair(v3.x), b3 = bfpair(v3.y);
                acc4.x += w0 * a0.x + w1 * a1.x + w2 * a2.x + w3 * a3.x;
                acc4.y += w0 * a0.y + w1 * a1.y + w2 * a2.y + w3 * a3.y;
                acc4.z += w0 * b0.x + w1 * b1.x + w2 * b2.x + w3 * b3.x;
                acc4.w += w0 * b0.y + w1 * b1.y + w2 * b2.y + w3 * b3.y;
            } else {
                float v0 = bf2f(hb[(size_t)s0 * CH + lane]);
                float v1 = bf2f(hb[(size_t)s1 * CH + lane]);
                float v2 = bf2f(hb[(size_t)s2 * CH + lane]);
                float v3 = bf2f(hb[(size_t)s3 * CH + lane]);
                acc1 += w0 * v0 + w1 * v1 + w2 * v2 + w3 * v3;
            }
        }
        for (; j < cnt; ++j) {
            int   sj = __shfl(sl, j);
            float w  = wls[wid][j * 5 + head];
            if constexpr (CH == 256) {
                uint2 hv = *(const uint2*)(hb + (size_t)sj * CH + lane * 4);
                float2 q0 = bfpair(hv.x), q1 = bfpair(hv.y);
                acc4.x += w * q0.x; acc4.y += w * q0.y;
                acc4.z += w * q1.x; acc4.w += w * q1.y;
            } else {
                acc1 += w * bf2f(hb[(size_t)sj * CH + lane]);
            }
        }
    }

    const float invd = 1.0f / (pickh(den, head) + 1e-16f);
    if constexpr (CH == 256) {
        int c0 = lane * 4;
        float o0 = fmaxf(acc4.x * invd + bias[c0 + 0], 0.f);
        float o1 = fmaxf(acc4.y * invd + bias[c0 + 1], 0.f);
        float o2 = fmaxf(acc4.z * invd + bias[c0 + 2], 0.f);
        float o3 = fmaxf(acc4.w * invd + bias[c0 + 3], 0.f);
        unsigned short h0 = bfr(o0), h1 = bfr(o1), h2 = bfr(o2), h3 = bfr(o3);
        unsigned short l0 = bfr(o0 - bf2f(h0)), l1 = bfr(o1 - bf2f(h1));
        unsigned short l2 = bfr(o2 - bf2f(h2)), l3 = bfr(o3 - bf2f(h3));
        *(uint2*)(out_hi + (size_t)node * CH + c0) =
            make_uint2((unsigned)h0 | ((unsigned)h1 << 16), (unsigned)h2 | ((unsigned)h3 << 16));
        *(uint2*)(out_lo + (size_t)node * CH + c0) =
            make_uint2((unsigned)l0 | ((unsigned)l1 << 16), (unsigned)l2 | ((unsigned)l3 << 16));
    } else {
        out[(size_t)node * CH + lane] = fmaxf(acc1 * invd + bias[lane], 0.f);
    }
}

// ---------------- graph boundaries + fused mean-pool/FC ----------------
__global__ void graph_starts_kernel(const int* __restrict__ batch, int* __restrict__ starts,
                                    int n, int ngraphs)
{
    int g = threadIdx.x;
    if (g > ngraphs) return;
    int lo = 0, hi = n;
    while (lo < hi) {
        int mid = (lo + hi) >> 1;
        if (batch[mid] < g) lo = mid + 1; else hi = mid;
    }
    starts[g] = lo;
}

__global__ __launch_bounds__(256)
void pool_fc_kernel(const float* __restrict__ feat, const int* __restrict__ starts,
                    const float* __restrict__ Wfc, const float* __restrict__ bfc,
                    float* __restrict__ out)
{
    __shared__ float4 part[16][16];
    __shared__ float pooled[64];
    const int g = blockIdx.x;
    const int t = threadIdx.x;
    const int q = t & 15, ns = t >> 4;
    const int s0 = starts[g], s1 = starts[g + 1];
    float4 acc = make_float4(0.f, 0.f, 0.f, 0.f);
    for (int i = s0 + ns; i < s1; i += 16)
        acc = f4add(acc, *(const float4*)(feat + (size_t)i * 64 + q * 4));
    part[ns][q] = acc;
    __syncthreads();
    if (t < 16) {
        float4 s = part[0][t];
#pragma unroll
        for (int k = 1; k < 16; ++k) s = f4add(s, part[k][t]);
        float inv = 1.0f / fmaxf((float)(s1 - s0), 1.0f);
        pooled[t * 4 + 0] = s.x * inv;
        pooled[t * 4 + 1] = s.y * inv;
        pooled[t * 4 + 2] = s.z * inv;
        pooled[t * 4 + 3] = s.w * inv;
    }
    __syncthreads();
    if (t < 2) {
        float a = bfc[t];
        for (int c = 0; c < 64; ++c) a += pooled[c] * Wfc[c * 2 + t];
        out[g * 2 + t] = a;
    }
}

// ---------------- launch ----------------
extern "C" void kernel_launch(void* const* d_in, const int* in_sizes, int n_in,
                              void* d_out, int out_size, void* d_ws, size_t ws_size,
                              hipStream_t stream)
{
    const float* x    = (const float*)d_in[0];
    const int*   ei   = (const int*)d_in[1];
    const int*   batch= (const int*)d_in[2];
    const float* W1   = (const float*)d_in[3];
    const float* as1  = (const float*)d_in[4];
    const float* ad1  = (const float*)d_in[5];
    const float* b1   = (const float*)d_in[6];
    const float* W2   = (const float*)d_in[7];
    const float* as2  = (const float*)d_in[8];
    const float* ad2  = (const float*)d_in[9];
    const float* b2   = (const float*)d_in[10];
    const float* Wfc  = (const float*)d_in[11];
    const float* bfc  = (const float*)d_in[12];
    float* out = (float*)d_out;

    const int N = in_sizes[2];          // 50000 nodes
    const int E = in_sizes[1] / 27;     // 400000 edges
    const int F = in_sizes[0] / N;      // 128

    char* ws = (char*)d_ws;
    unsigned short* h1b   = (unsigned short*)(ws + OFF_H1B);
    unsigned short* h2b   = (unsigned short*)(ws + OFF_H2B);
    float*          out2  = (float*)(ws + OFF_OUT2);
    unsigned short* xhi   = (unsigned short*)(ws + OFF_XHI);
    unsigned short* xlo   = (unsigned short*)(ws + OFF_XLO);
    unsigned short* o1hi  = (unsigned short*)(ws + OFF_O1HI);
    unsigned short* o1lo  = (unsigned short*)(ws + OFF_O1LO);
    unsigned short* w1th  = (unsigned short*)(ws + OFF_W1TH);
    unsigned short* w1tl  = (unsigned short*)(ws + OFF_W1TL);
    unsigned short* w2th  = (unsigned short*)(ws + OFF_W2TH);
    unsigned short* w2tl  = (unsigned short*)(ws + OFF_W2TL);
    float* al_s  = (float*)(ws + OFF_AS);
    float* al_d  = (float*)(ws + OFF_AD);
    int*   rp    = (int*)(ws + OFF_RP);     // (2N+1) entries; layer2 view = rp+N
    int*   cur   = (int*)(ws + OFF_CUR);    // 2N
    int*   cnt   = (int*)(ws + OFF_CNT);    // 2N
    int*   csr   = (int*)(ws + OFF_CSR);    // 2E (global positions)
    int*   strt  = (int*)(ws + OFF_STRT);
    int*   bsum  = (int*)(ws + OFF_BSUM);
    int*   boff  = (int*)(ws + OFF_BOFF);

    const int e2grid = (2 * E + 255) / 256;
    const int NB2    = (2 * N + 1023) / 1024;   // 98 blocks

    // ---- splits ----
    split_kernel<<<2048, 256, 0, stream>>>(x, xhi, xlo, N * F / 4);
    wsplit_kernel<<<(F * HEADS * 64 + 255) / 256, 256, 0, stream>>>(W1, w1th, w1tl, F, HEADS * 64);
    wsplit_kernel<<<(HEADS * 64 * HEADS * 16 + 255) / 256, 256, 0, stream>>>(W2, w2th, w2tl, HEADS * 64, HEADS * 16);

    // ---- fused CSR build for both layers ----
    hipMemsetAsync(cnt, 0, (size_t)2 * N * sizeof(int), stream);
    count2_kernel<<<e2grid, 256, 0, stream>>>(ei + 26 * (size_t)E, ei + 16 * (size_t)E, cnt, N, E);
    scan_block_kernel<<<NB2, 1024, 0, stream>>>(cnt, rp, bsum, 2 * N);
    scan_tops_kernel<<<1, 256, 0, stream>>>(bsum, boff, rp, NB2, 2 * N);
    scan_add_kernel<<<NB2, 1024, 0, stream>>>(boff, rp, cur, 2 * N);
    scatter2_kernel<<<e2grid, 256, 0, stream>>>(ei + 17 * (size_t)E, ei + 26 * (size_t)E,
                                                ei + 15 * (size_t)E, ei + 16 * (size_t)E,
                                                cur, csr, N, E);

    // ---- layer 1: MFMA GEMM (M=50000, K=128, Ncols=256) -> bf16 h1 ----
    {
        dim3 g((N + 127) / 128, 2);
        mfma_gemm_gat<128, 128, 128, 2, 2, 64><<<g, 256, 0, stream>>>(
            xhi, xlo, w1th, w1tl, h1b, as1, ad1, al_s, al_d, N, HEADS * 64);
    }
    gat_agg<256><<<(N + 3) / 4, 256, 0, stream>>>(h1b, al_s, al_d, rp, csr, b1,
                                                  nullptr, o1hi, o1lo, N);

    // ---- layer 2: MFMA GEMM (M=50000, K=256, Ncols=64) -> bf16 h2 ----
    {
        dim3 g((N + 63) / 64, 1);
        mfma_gemm_gat<64, 64, 256, 2, 2, 16><<<g, 256, 0, stream>>>(
            o1hi, o1lo, w2th, w2tl, h2b, as2, ad2, al_s, al_d, N, HEADS * 16);
    }
    gat_agg<64><<<(N + 3) / 4, 256, 0, stream>>>(h2b, al_s, al_d, rp + N, csr, b2,
                                                 out2, nullptr, nullptr, N);

    // ---- pool + fc ----
    graph_starts_kernel<<<1, 65, 0, stream>>>(batch, strt, N, 64);
    pool_fc_kernel<<<64, 256, 0, stream>>>(out2, strt, Wfc, bfc, out);
}

// Round 9
// 224.293 us; speedup vs baseline: 1.7996x; 1.0686x over previous
//
#include <hip/hip_runtime.h>
#include <math.h>

#define HEADS 4
#define NEG_SLOPE 0.2f

// ---------------- workspace layout (bytes) ----------------
static constexpr size_t OFF_H1B  = 0;
static constexpr size_t OFF_H2B  = 0;
static constexpr size_t OFF_OUT2 = 6400000;
static constexpr size_t OFF_XHI  = 25600000;
static constexpr size_t OFF_XLO  = 38400000;
static constexpr size_t OFF_O1HI = 25600000;   // aliases xhi/xlo (dead by then)
static constexpr size_t OFF_O1LO = 51200000;
static constexpr size_t OFF_W1TH = 76800000;   // 256x128 bf16 = 64KB
static constexpr size_t OFF_W1TL = 76865536;
static constexpr size_t OFF_W2TH = 76931072;   // 64x256 bf16 = 32KB
static constexpr size_t OFF_W2TL = 76963840;
static constexpr size_t OFF_AS   = 77000000;   // 800,000
static constexpr size_t OFF_AD   = 77800000;   // 800,000
static constexpr size_t OFF_RP   = 78600064;   // (2N+1) ints
static constexpr size_t OFF_CUR  = 79000128;
static constexpr size_t OFF_CNT  = 79400128;
static constexpr size_t OFF_CSR  = 79800128;   // 2E ints
static constexpr size_t OFF_STRT = 83000128;
static constexpr size_t OFF_BSUM = 83000448;
static constexpr size_t OFF_BOFF = 83001472;

typedef __attribute__((ext_vector_type(8))) short short8;
typedef __attribute__((ext_vector_type(4))) float f32x4;

// ---------------- helpers ----------------
__device__ __forceinline__ float4 f4add(float4 a, float4 b) {
    return make_float4(a.x + b.x, a.y + b.y, a.z + b.z, a.w + b.w);
}
__device__ __forceinline__ float lrelu(float x) { return x > 0.f ? x : NEG_SLOPE * x; }
__device__ __forceinline__ float4 f4lrelu(float4 a) {
    return make_float4(lrelu(a.x), lrelu(a.y), lrelu(a.z), lrelu(a.w));
}
__device__ __forceinline__ float4 f4exp(float4 a) {
    return make_float4(__expf(a.x), __expf(a.y), __expf(a.z), __expf(a.w));
}
__device__ __forceinline__ float pickh(float4 v, int head) {
    float r = v.x;
    r = head == 1 ? v.y : r;
    r = head == 2 ? v.z : r;
    r = head == 3 ? v.w : r;
    return r;
}
__device__ __forceinline__ unsigned short bfr(float x) {
    union { float f; unsigned u; } c; c.f = x;
    unsigned r = c.u + 0x7FFFu + ((c.u >> 16) & 1u);
    return (unsigned short)(r >> 16);
}
__device__ __forceinline__ float bf2f(unsigned short h) {
    union { unsigned u; float f; } c; c.u = ((unsigned)h) << 16;
    return c.f;
}
__device__ __forceinline__ float2 bfpair(unsigned u) {
    union { unsigned a; float f; } lo, hi;
    lo.a = u << 16;
    hi.a = u & 0xffff0000u;
    return make_float2(lo.f, hi.f);
}

// ---------------- split kernels ----------------
__global__ void split_kernel(const float* __restrict__ in, unsigned short* __restrict__ hi,
                             unsigned short* __restrict__ lo, int n4)
{
    int i = blockIdx.x * 256 + threadIdx.x;
    const int stride = gridDim.x * 256;
    for (; i < n4; i += stride) {
        float4 v = ((const float4*)in)[i];
        unsigned short h0 = bfr(v.x), h1 = bfr(v.y), h2 = bfr(v.z), h3 = bfr(v.w);
        unsigned short l0 = bfr(v.x - bf2f(h0)), l1 = bfr(v.y - bf2f(h1));
        unsigned short l2 = bfr(v.z - bf2f(h2)), l3 = bfr(v.w - bf2f(h3));
        ((uint2*)hi)[i] = make_uint2((unsigned)h0 | ((unsigned)h1 << 16),
                                     (unsigned)h2 | ((unsigned)h3 << 16));
        ((uint2*)lo)[i] = make_uint2((unsigned)l0 | ((unsigned)l1 << 16),
                                     (unsigned)l2 | ((unsigned)l3 << 16));
    }
}

__global__ void wsplit_kernel(const float* __restrict__ W, unsigned short* __restrict__ hiT,
                              unsigned short* __restrict__ loT, int K, int N)
{
    int idx = blockIdx.x * 256 + threadIdx.x;
    if (idx >= K * N) return;
    int k = idx / N, n = idx - k * N;
    float v = W[idx];
    unsigned short h = bfr(v);
    hiT[(size_t)n * K + k] = h;
    loT[(size_t)n * K + k] = bfr(v - bf2f(h));
}

// ---------------- MFMA GEMM with GAT-alpha epilogue ----------------
template<int BM, int BN, int KDIM, int WR, int WC, int CPH>
__global__ __launch_bounds__(256, 2)
void mfma_gemm_gat(const unsigned short* __restrict__ Ahi, const unsigned short* __restrict__ Alo,
                   const unsigned short* __restrict__ BThi, const unsigned short* __restrict__ BTlo,
                   unsigned short* __restrict__ Cb,
                   const float* __restrict__ avec_s, const float* __restrict__ avec_d,
                   float* __restrict__ alpha_s, float* __restrict__ alpha_d,
                   int M, int N)
{
    constexpr int BK    = 32;
    constexpr int WROWS = BM / WR;
    constexpr int WCOLS = BN / WC;
    constexpr int FR    = WROWS / 16;
    constexpr int FC    = WCOLS / 16;
    constexpr int AP    = (BM * (BK / 8)) / 256;
    constexpr int BP    = (BN * (BK / 8)) / 256;
    static_assert(AP >= 1 && BP >= 1, "tile too small");

    __shared__ short As_hi[BM * BK], As_lo[BM * BK];
    __shared__ short Bs_hi[BN * BK], Bs_lo[BN * BK];

    const int tid  = threadIdx.x;
    const int w    = tid >> 6, lane = tid & 63;
    const int wr   = w / WC, wc = w % WC;
    const int lrow = lane & 15, lk = lane >> 4;
    const int m0   = blockIdx.x * BM, n0 = blockIdx.y * BN;

    f32x4 acc[FR][FC];
#pragma unroll
    for (int i = 0; i < FR; ++i)
#pragma unroll
        for (int j = 0; j < FC; ++j) acc[i][j] = (f32x4){0.f, 0.f, 0.f, 0.f};

    short8 rAh[AP], rAl[AP], rBh[BP], rBl[BP];

    auto LOAD = [&](int kb) {
#pragma unroll
        for (int p = 0; p < AP; ++p) {
            int id = p * 256 + tid;
            int r = id >> 2, c = id & 3;
            int row = m0 + r; row = row < M ? row : M - 1;
            size_t off = (size_t)row * KDIM + kb + c * 8;
            rAh[p] = *(const short8*)(Ahi + off);
            rAl[p] = *(const short8*)(Alo + off);
        }
#pragma unroll
        for (int p = 0; p < BP; ++p) {
            int id = p * 256 + tid;
            int r = id >> 2, c = id & 3;
            size_t off = (size_t)(n0 + r) * KDIM + kb + c * 8;
            rBh[p] = *(const short8*)(BThi + off);
            rBl[p] = *(const short8*)(BTlo + off);
        }
    };
    auto STORE = [&]() {
#pragma unroll
        for (int p = 0; p < AP; ++p) {
            int id = p * 256 + tid;
            int r = id >> 2, c = id & 3;
            *(short8*)(&As_hi[r * BK + c * 8]) = rAh[p];
            *(short8*)(&As_lo[r * BK + c * 8]) = rAl[p];
        }
#pragma unroll
        for (int p = 0; p < BP; ++p) {
            int id = p * 256 + tid;
            int r = id >> 2, c = id & 3;
            *(short8*)(&Bs_hi[r * BK + c * 8]) = rBh[p];
            *(short8*)(&Bs_lo[r * BK + c * 8]) = rBl[p];
        }
    };

    constexpr int NT = KDIM / BK;
    LOAD(0);
    for (int t = 0; t < NT; ++t) {
        STORE();
        __syncthreads();
        if (t + 1 < NT) LOAD((t + 1) * BK);

        short8 afh[FR], afl[FR], bfh[FC], bfl[FC];
#pragma unroll
        for (int fr = 0; fr < FR; ++fr) {
            int r = wr * WROWS + fr * 16 + lrow;
            afh[fr] = *(const short8*)(&As_hi[r * BK + lk * 8]);
            afl[fr] = *(const short8*)(&As_lo[r * BK + lk * 8]);
        }
#pragma unroll
        for (int fc = 0; fc < FC; ++fc) {
            int r = wc * WCOLS + fc * 16 + lrow;
            bfh[fc] = *(const short8*)(&Bs_hi[r * BK + lk * 8]);
            bfl[fc] = *(const short8*)(&Bs_lo[r * BK + lk * 8]);
        }
#pragma unroll
        for (int fr = 0; fr < FR; ++fr)
#pragma unroll
            for (int fc = 0; fc < FC; ++fc) {
                acc[fr][fc] = __builtin_amdgcn_mfma_f32_16x16x32_bf16(afh[fr], bfh[fc], acc[fr][fc], 0, 0, 0);
                acc[fr][fc] = __builtin_amdgcn_mfma_f32_16x16x32_bf16(afh[fr], bfl[fc], acc[fr][fc], 0, 0, 0);
                acc[fr][fc] = __builtin_amdgcn_mfma_f32_16x16x32_bf16(afl[fr], bfh[fc], acc[fr][fc], 0, 0, 0);
            }
        __syncthreads();
    }

#pragma unroll
    for (int fr = 0; fr < FR; ++fr) {
        const int rbase = m0 + wr * WROWS + fr * 16 + lk * 4;
        float ps[4] = {0.f, 0.f, 0.f, 0.f}, pd[4] = {0.f, 0.f, 0.f, 0.f};
#pragma unroll
        for (int fc = 0; fc < FC; ++fc) {
            const int gc   = n0 + wc * WCOLS + fc * 16 + lrow;
            const int head = gc / CPH, ci = gc % CPH;
            const float asv = avec_s[head * CPH + ci];
            const float adv = avec_d[head * CPH + ci];
#pragma unroll
            for (int rg = 0; rg < 4; ++rg) {
                int row = rbase + rg;
                float v = acc[fr][fc][rg];
                if (row < M) Cb[(size_t)row * N + gc] = bfr(v);
                ps[rg] += v * asv;
                pd[rg] += v * adv;
            }
            if constexpr (CPH == 16) {
#pragma unroll
                for (int rg = 0; rg < 4; ++rg) {
                    float s = ps[rg], d = pd[rg];
#pragma unroll
                    for (int m = 1; m <= 8; m <<= 1) {
                        s += __shfl_xor(s, m);
                        d += __shfl_xor(d, m);
                    }
                    if (lrow == 0 && rbase + rg < M) {
                        alpha_s[(size_t)(rbase + rg) * HEADS + head] = s;
                        alpha_d[(size_t)(rbase + rg) * HEADS + head] = d;
                    }
                    ps[rg] = 0.f; pd[rg] = 0.f;
                }
            }
        }
        if constexpr (CPH != 16) {
            const int head = (n0 + wc * WCOLS) / CPH;
#pragma unroll
            for (int rg = 0; rg < 4; ++rg) {
                float s = ps[rg], d = pd[rg];
#pragma unroll
                for (int m = 1; m <= 8; m <<= 1) {
                    s += __shfl_xor(s, m);
                    d += __shfl_xor(d, m);
                }
                if (lrow == 0 && rbase + rg < M) {
                    alpha_s[(size_t)(rbase + rg) * HEADS + head] = s;
                    alpha_d[(size_t)(rbase + rg) * HEADS + head] = d;
                }
            }
        }
    }
}

// ---------------- fused 2-layer CSR build ----------------
__global__ void count2_kernel(const int* __restrict__ dst1, const int* __restrict__ dst2,
                              int* __restrict__ counts, int N, int E)
{
    int e = blockIdx.x * 256 + threadIdx.x;
    if (e < E)            atomicAdd(&counts[dst1[e]], 1);
    else if (e < 2 * E)   atomicAdd(&counts[N + dst2[e - E]], 1);
}

__global__ void scatter2_kernel(const int* __restrict__ src1, const int* __restrict__ dst1,
                                const int* __restrict__ src2, const int* __restrict__ dst2,
                                int* __restrict__ cursor, int* __restrict__ csr, int N, int E)
{
    int e = blockIdx.x * 256 + threadIdx.x;
    if (e < E) {
        int pos = atomicAdd(&cursor[dst1[e]], 1);
        csr[pos] = src1[e];
    } else if (e < 2 * E) {
        int pos = atomicAdd(&cursor[N + dst2[e - E]], 1);
        csr[pos] = src2[e - E];
    }
}

// ---------------- parallel scan (3 kernels) ----------------
__global__ __launch_bounds__(1024)
void scan_block_kernel(const int* __restrict__ counts, int* __restrict__ excl_out,
                       int* __restrict__ bsum, int n)
{
    __shared__ int wsum[16];
    const int t = threadIdx.x, lane = t & 63, w = t >> 6;
    const int i = blockIdx.x * 1024 + t;
    int v = (i < n) ? counts[i] : 0;
    int x = v;
#pragma unroll
    for (int d = 1; d < 64; d <<= 1) {
        int y = __shfl_up(x, d);
        if (lane >= d) x += y;
    }
    if (lane == 63) wsum[w] = x;
    __syncthreads();
    if (t < 16) {
        int s = wsum[t];
#pragma unroll
        for (int d = 1; d < 16; d <<= 1) {
            int y = __shfl_up(s, d);
            if (t >= d) s += y;
        }
        wsum[t] = s;
    }
    __syncthreads();
    int wbase = (w > 0) ? wsum[w - 1] : 0;
    if (i < n) excl_out[i] = wbase + x - v;
    if (t == 1023) bsum[blockIdx.x] = wsum[15];
}

__global__ __launch_bounds__(256)
void scan_tops_kernel(const int* __restrict__ bsum, int* __restrict__ boff,
                      int* __restrict__ row_ptr, int nb, int ntot)
{
    __shared__ int wtot[4];
    const int t = threadIdx.x, lane = t & 63, w = t >> 6;
    int v = (t < nb) ? bsum[t] : 0;
    int x = v;
#pragma unroll
    for (int d = 1; d < 64; d <<= 1) {
        int y = __shfl_up(x, d);
        if (lane >= d) x += y;
    }
    if (lane == 63) wtot[w] = x;
    __syncthreads();
    int wbase = 0;
    for (int k = 0; k < w; ++k) wbase += wtot[k];
    if (t < nb) boff[t] = wbase + x - v;
    if (t == 255) row_ptr[ntot] = wbase + x;
}

__global__ __launch_bounds__(1024)
void scan_add_kernel(const int* __restrict__ boff, int* __restrict__ row_ptr,
                     int* __restrict__ cursor, int n)
{
    const int i = blockIdx.x * 1024 + threadIdx.x;
    if (i < n) {
        int r = row_ptr[i] + boff[blockIdx.x];
        row_ptr[i] = r;
        cursor[i]  = r;
    }
}

// ---------------- GAT softmax + aggregation ----------------
// S lanes per node (subgroup). Each lane owns CPL=CH/S channels, loaded as one
// 16B/8B vector. j-loop 8-deep unrolled with zero-weight padding (inactive lanes
// park on row 0, w=0) -> no serial remainder, 8 gathers in flight per lane.
// No max-shift (|e| is O(1), far from f32 exp limits).
template<int CH, int S>
__global__ __launch_bounds__(256)
void gat_agg(const unsigned short* __restrict__ hb, const float* __restrict__ alpha_s,
             const float* __restrict__ alpha_d, const int* __restrict__ row_ptr,
             const int* __restrict__ csr_src, const float* __restrict__ bias,
             float* __restrict__ out, unsigned short* __restrict__ out_hi,
             unsigned short* __restrict__ out_lo, int n)
{
    constexpr int CPL = CH / S;      // 8 (CH=256) or 4 (CH=64)
    constexpr int NSG = 256 / S;     // subgroups per block
    __shared__ float wls[NSG][S * 5];
    const int tid    = threadIdx.x;
    const int sub    = tid / S;
    const int i      = tid % S;          // lane within subgroup
    const int lane64 = tid & 63;
    const int base   = lane64 & ~(S - 1);
    const int node   = blockIdx.x * NSG + sub;
    if (node >= n) return;
    const int head = (i * CPL) / (CH / 4);
    const int p0 = row_ptr[node], p1 = row_ptr[node + 1];
    const int deg = p1 - p0;

    const float4 asn = *(const float4*)(alpha_s + (size_t)node * 4);
    const float4 adn = *(const float4*)(alpha_d + (size_t)node * 4);
    float4 den = f4exp(f4lrelu(f4add(asn, adn)));   // self-loop term
    const float wse = pickh(den, head);

    float acc[CPL];
    if constexpr (CPL == 8) {
        uint4 hv = *(const uint4*)(hb + (size_t)node * CH + i * 8);
        float2 q0 = bfpair(hv.x), q1 = bfpair(hv.y), q2 = bfpair(hv.z), q3 = bfpair(hv.w);
        acc[0] = wse * q0.x; acc[1] = wse * q0.y; acc[2] = wse * q1.x; acc[3] = wse * q1.y;
        acc[4] = wse * q2.x; acc[5] = wse * q2.y; acc[6] = wse * q3.x; acc[7] = wse * q3.y;
    } else {
        uint2 hv = *(const uint2*)(hb + (size_t)node * CH + i * 4);
        float2 q0 = bfpair(hv.x), q1 = bfpair(hv.y);
        acc[0] = wse * q0.x; acc[1] = wse * q0.y; acc[2] = wse * q1.x; acc[3] = wse * q1.y;
    }

    for (int ch = 0; ch < deg; ch += S) {
        const int cnt = min(S, deg - ch);
        float4 w4 = make_float4(0.f, 0.f, 0.f, 0.f);
        int sl = 0;
        if (i < cnt) {
            sl = csr_src[p0 + ch + i];
            float4 al = *(const float4*)(alpha_s + (size_t)sl * 4);
            w4 = f4exp(f4lrelu(f4add(al, adn)));
        }
        float4 t = w4;
#pragma unroll
        for (int d = S / 2; d >= 1; d >>= 1) {
            t.x += __shfl_xor(t.x, d);
            t.y += __shfl_xor(t.y, d);
            t.z += __shfl_xor(t.z, d);
            t.w += __shfl_xor(t.w, d);
        }
        den = f4add(den, t);
        wls[sub][i * 5 + 0] = w4.x;
        wls[sub][i * 5 + 1] = w4.y;
        wls[sub][i * 5 + 2] = w4.z;
        wls[sub][i * 5 + 3] = w4.w;

        const int padded = (cnt + 7) & ~7;
        for (int j = 0; j < padded; j += 8) {
            int   sk[8];
            float wk[8];
#pragma unroll
            for (int k = 0; k < 8; ++k) {
                sk[k] = __shfl(sl, base + j + k);
                wk[k] = wls[sub][(j + k) * 5 + head];
            }
            if constexpr (CPL == 8) {
                uint4 v[8];
#pragma unroll
                for (int k = 0; k < 8; ++k)
                    v[k] = *(const uint4*)(hb + (size_t)sk[k] * CH + i * 8);
#pragma unroll
                for (int k = 0; k < 8; ++k) {
                    float2 q0 = bfpair(v[k].x), q1 = bfpair(v[k].y);
                    float2 q2 = bfpair(v[k].z), q3 = bfpair(v[k].w);
                    acc[0] += wk[k] * q0.x; acc[1] += wk[k] * q0.y;
                    acc[2] += wk[k] * q1.x; acc[3] += wk[k] * q1.y;
                    acc[4] += wk[k] * q2.x; acc[5] += wk[k] * q2.y;
                    acc[6] += wk[k] * q3.x; acc[7] += wk[k] * q3.y;
                }
            } else {
                uint2 v[8];
#pragma unroll
                for (int k = 0; k < 8; ++k)
                    v[k] = *(const uint2*)(hb + (size_t)sk[k] * CH + i * 4);
#pragma unroll
                for (int k = 0; k < 8; ++k) {
                    float2 q0 = bfpair(v[k].x), q1 = bfpair(v[k].y);
                    acc[0] += wk[k] * q0.x; acc[1] += wk[k] * q0.y;
                    acc[2] += wk[k] * q1.x; acc[3] += wk[k] * q1.y;
                }
            }
        }
    }

    const float invd = 1.0f / (pickh(den, head) + 1e-16f);
    const int c0 = i * CPL;
    if constexpr (CPL == 8) {
        float o[8];
        unsigned short oh[8], ol[8];
#pragma unroll
        for (int k = 0; k < 8; ++k) {
            o[k] = fmaxf(acc[k] * invd + bias[c0 + k], 0.f);
            oh[k] = bfr(o[k]);
            ol[k] = bfr(o[k] - bf2f(oh[k]));
        }
        uint4 ph, pl;
        ph.x = (unsigned)oh[0] | ((unsigned)oh[1] << 16);
        ph.y = (unsigned)oh[2] | ((unsigned)oh[3] << 16);
        ph.z = (unsigned)oh[4] | ((unsigned)oh[5] << 16);
        ph.w = (unsigned)oh[6] | ((unsigned)oh[7] << 16);
        pl.x = (unsigned)ol[0] | ((unsigned)ol[1] << 16);
        pl.y = (unsigned)ol[2] | ((unsigned)ol[3] << 16);
        pl.z = (unsigned)ol[4] | ((unsigned)ol[5] << 16);
        pl.w = (unsigned)ol[6] | ((unsigned)ol[7] << 16);
        *(uint4*)(out_hi + (size_t)node * CH + c0) = ph;
        *(uint4*)(out_lo + (size_t)node * CH + c0) = pl;
    } else {
        float4 o;
        o.x = fmaxf(acc[0] * invd + bias[c0 + 0], 0.f);
        o.y = fmaxf(acc[1] * invd + bias[c0 + 1], 0.f);
        o.z = fmaxf(acc[2] * invd + bias[c0 + 2], 0.f);
        o.w = fmaxf(acc[3] * invd + bias[c0 + 3], 0.f);
        *(float4*)(out + (size_t)node * CH + c0) = o;
    }
}

// ---------------- graph boundaries + fused mean-pool/FC ----------------
__global__ void graph_starts_kernel(const int* __restrict__ batch, int* __restrict__ starts,
                                    int n, int ngraphs)
{
    int g = threadIdx.x;
    if (g > ngraphs) return;
    int lo = 0, hi = n;
    while (lo < hi) {
        int mid = (lo + hi) >> 1;
        if (batch[mid] < g) lo = mid + 1; else hi = mid;
    }
    starts[g] = lo;
}

__global__ __launch_bounds__(256)
void pool_fc_kernel(const float* __restrict__ feat, const int* __restrict__ starts,
                    const float* __restrict__ Wfc, const float* __restrict__ bfc,
                    float* __restrict__ out)
{
    __shared__ float4 part[16][16];
    __shared__ float pooled[64];
    const int g = blockIdx.x;
    const int t = threadIdx.x;
    const int q = t & 15, ns = t >> 4;
    const int s0 = starts[g], s1 = starts[g + 1];
    float4 acc = make_float4(0.f, 0.f, 0.f, 0.f);
    for (int i = s0 + ns; i < s1; i += 16)
        acc = f4add(acc, *(const float4*)(feat + (size_t)i * 64 + q * 4));
    part[ns][q] = acc;
    __syncthreads();
    if (t < 16) {
        float4 s = part[0][t];
#pragma unroll
        for (int k = 1; k < 16; ++k) s = f4add(s, part[k][t]);
        float inv = 1.0f / fmaxf((float)(s1 - s0), 1.0f);
        pooled[t * 4 + 0] = s.x * inv;
        pooled[t * 4 + 1] = s.y * inv;
        pooled[t * 4 + 2] = s.z * inv;
        pooled[t * 4 + 3] = s.w * inv;
    }
    __syncthreads();
    if (t < 2) {
        float a = bfc[t];
        for (int c = 0; c < 64; ++c) a += pooled[c] * Wfc[c * 2 + t];
        out[g * 2 + t] = a;
    }
}

// ---------------- launch ----------------
extern "C" void kernel_launch(void* const* d_in, const int* in_sizes, int n_in,
                              void* d_out, int out_size, void* d_ws, size_t ws_size,
                              hipStream_t stream)
{
    const float* x    = (const float*)d_in[0];
    const int*   ei   = (const int*)d_in[1];
    const int*   batch= (const int*)d_in[2];
    const float* W1   = (const float*)d_in[3];
    const float* as1  = (const float*)d_in[4];
    const float* ad1  = (const float*)d_in[5];
    const float* b1   = (const float*)d_in[6];
    const float* W2   = (const float*)d_in[7];
    const float* as2  = (const float*)d_in[8];
    const float* ad2  = (const float*)d_in[9];
    const float* b2   = (const float*)d_in[10];
    const float* Wfc  = (const float*)d_in[11];
    const float* bfc  = (const float*)d_in[12];
    float* out = (float*)d_out;

    const int N = in_sizes[2];          // 50000 nodes
    const int E = in_sizes[1] / 27;     // 400000 edges
    const int F = in_sizes[0] / N;      // 128

    char* ws = (char*)d_ws;
    unsigned short* h1b   = (unsigned short*)(ws + OFF_H1B);
    unsigned short* h2b   = (unsigned short*)(ws + OFF_H2B);
    float*          out2  = (float*)(ws + OFF_OUT2);
    unsigned short* xhi   = (unsigned short*)(ws + OFF_XHI);
    unsigned short* xlo   = (unsigned short*)(ws + OFF_XLO);
    unsigned short* o1hi  = (unsigned short*)(ws + OFF_O1HI);
    unsigned short* o1lo  = (unsigned short*)(ws + OFF_O1LO);
    unsigned short* w1th  = (unsigned short*)(ws + OFF_W1TH);
    unsigned short* w1tl  = (unsigned short*)(ws + OFF_W1TL);
    unsigned short* w2th  = (unsigned short*)(ws + OFF_W2TH);
    unsigned short* w2tl  = (unsigned short*)(ws + OFF_W2TL);
    float* al_s  = (float*)(ws + OFF_AS);
    float* al_d  = (float*)(ws + OFF_AD);
    int*   rp    = (int*)(ws + OFF_RP);     // (2N+1) entries; layer2 view = rp+N
    int*   cur   = (int*)(ws + OFF_CUR);    // 2N
    int*   cnt   = (int*)(ws + OFF_CNT);    // 2N
    int*   csr   = (int*)(ws + OFF_CSR);    // 2E (global positions)
    int*   strt  = (int*)(ws + OFF_STRT);
    int*   bsum  = (int*)(ws + OFF_BSUM);
    int*   boff  = (int*)(ws + OFF_BOFF);

    const int e2grid = (2 * E + 255) / 256;
    const int NB2    = (2 * N + 1023) / 1024;   // 98 blocks

    // ---- splits ----
    split_kernel<<<2048, 256, 0, stream>>>(x, xhi, xlo, N * F / 4);
    wsplit_kernel<<<(F * HEADS * 64 + 255) / 256, 256, 0, stream>>>(W1, w1th, w1tl, F, HEADS * 64);
    wsplit_kernel<<<(HEADS * 64 * HEADS * 16 + 255) / 256, 256, 0, stream>>>(W2, w2th, w2tl, HEADS * 64, HEADS * 16);

    // ---- fused CSR build for both layers ----
    hipMemsetAsync(cnt, 0, (size_t)2 * N * sizeof(int), stream);
    count2_kernel<<<e2grid, 256, 0, stream>>>(ei + 26 * (size_t)E, ei + 16 * (size_t)E, cnt, N, E);
    scan_block_kernel<<<NB2, 1024, 0, stream>>>(cnt, rp, bsum, 2 * N);
    scan_tops_kernel<<<1, 256, 0, stream>>>(bsum, boff, rp, NB2, 2 * N);
    scan_add_kernel<<<NB2, 1024, 0, stream>>>(boff, rp, cur, 2 * N);
    scatter2_kernel<<<e2grid, 256, 0, stream>>>(ei + 17 * (size_t)E, ei + 26 * (size_t)E,
                                                ei + 15 * (size_t)E, ei + 16 * (size_t)E,
                                                cur, csr, N, E);

    // ---- layer 1: MFMA GEMM (M=50000, K=128, Ncols=256) -> bf16 h1 ----
    {
        dim3 g((N + 127) / 128, 2);
        mfma_gemm_gat<128, 128, 128, 2, 2, 64><<<g, 256, 0, stream>>>(
            xhi, xlo, w1th, w1tl, h1b, as1, ad1, al_s, al_d, N, HEADS * 64);
    }
    gat_agg<256, 32><<<(N + 7) / 8, 256, 0, stream>>>(h1b, al_s, al_d, rp, csr, b1,
                                                      nullptr, o1hi, o1lo, N);

    // ---- layer 2: MFMA GEMM (M=50000, K=256, Ncols=64) -> bf16 h2 ----
    {
        dim3 g((N + 63) / 64, 1);
        mfma_gemm_gat<64, 64, 256, 2, 2, 16><<<g, 256, 0, stream>>>(
            o1hi, o1lo, w2th, w2tl, h2b, as2, ad2, al_s, al_d, N, HEADS * 16);
    }
    gat_agg<64, 16><<<(N + 15) / 16, 256, 0, stream>>>(h2b, al_s, al_d, rp + N, csr, b2,
                                                       out2, nullptr, nullptr, N);

    // ---- pool + fc ----
    graph_starts_kernel<<<1, 65, 0, stream>>>(batch, strt, N, 64);
    pool_fc_kernel<<<64, 256, 0, stream>>>(out2, strt, Wfc, bfc, out);
}